// Round 6
// baseline (2102.144 us; speedup 1.0000x reference)
//
#include <hip/hip_runtime.h>
#include <cmath>

// Problem constants
constexpr int kN   = 4096;
constexpr int kIN  = 3000;
constexpr int kINp = 3072;   // kIN padded to 128-multiple
constexpr int kLAT = 64;

enum { SL = 0, FEAT, ALN, FXA, FXB, SM1, SM2, SPS, NSLOT };

typedef __bf16 bf16x8 __attribute__((ext_vector_type(8)));
typedef float f32x4 __attribute__((ext_vector_type(4)));
typedef unsigned short u16x8 __attribute__((ext_vector_type(8)));
typedef unsigned short u16x4 __attribute__((ext_vector_type(4)));

// ---------------- reduction helpers ----------------
template<bool IS_MAX>
__device__ __forceinline__ float blk_red(float v) {
  __shared__ float buf[8];
  #pragma unroll
  for (int s = 32; s > 0; s >>= 1) {
    float o = __shfl_down(v, s, 64);
    v = IS_MAX ? fmaxf(v, o) : (v + o);
  }
  int lane = threadIdx.x & 63, wv = threadIdx.x >> 6, nw = blockDim.x >> 6;
  __syncthreads();
  if (lane == 0) buf[wv] = v;
  __syncthreads();
  float r = buf[0];
  for (int i = 1; i < nw; i++) r = IS_MAX ? fmaxf(r, buf[i]) : (r + buf[i]);
  return r;
}

__device__ __forceinline__ float wave_red_sum(float v) {
  #pragma unroll
  for (int s = 32; s > 0; s >>= 1) v += __shfl_down(v, s, 64);
  return v;
}

// fp32 -> bf16 RNE ; bf16 -> fp32
__device__ __forceinline__ unsigned short f2bf(float f) {
  unsigned u = __builtin_bit_cast(unsigned, f);
  u += 0x7fffu + ((u >> 16) & 1u);
  return (unsigned short)(u >> 16);
}
__device__ __forceinline__ float bf2f(unsigned short h) {
  return __builtin_bit_cast(float, (unsigned)h << 16);
}

// async global->LDS, 16B per lane
__device__ __forceinline__ void gload16(const unsigned short* g, unsigned short* l) {
  __builtin_amdgcn_global_load_lds(
      (const __attribute__((address_space(1))) unsigned int*)g,
      (__attribute__((address_space(3))) unsigned int*)l, 16, 0, 0);
}

// ============================================================================
// 256x256-tile 8-phase bf16 MFMA GEMM: C = A @ Bt^T   (K multiple of 128)
// A: [4096][K] bf16 (ldA=K). Bt: [Ncpad][K] bf16 (ldBt=K). M fixed 4096.
// 512 threads = 8 waves (2M x 4N), per-wave C 128x64. BK=64, 2 K-tiles/iter.
// LDS 128KB: 2 buf x 4 regions {Ak0,Bk0,Ak1,Bk1} x 16KB (256 rows x 32 k).
// Swizzle: 16B slot ^= (row>>1)&3 (write via pre-swizzled global src; read XOR).
// Counted vmcnt: steady {p0:8, p1:6, p4:8, p5:6}; peeled last {8,6,4,0}.
// EPI 0: Cb = bf16(acc / rowdiv[r]);  EPI 2: slot += wgt*sum (X - acc/rd/cd)^2
// ============================================================================
#define VMW(n) asm volatile("s_waitcnt vmcnt(" #n ")" ::: "memory")

template<int EPI, int XBF>
__global__ __launch_bounds__(512, 2)
void g8_mfma_k(const unsigned short* __restrict__ A, const unsigned short* __restrict__ Bt,
               unsigned short* __restrict__ Cb, const void* __restrict__ Xv,
               const float* __restrict__ rowdiv, const float* __restrict__ coldiv,
               float* __restrict__ slot, int Nc, int K, int ldX, int sym)
{
  __shared__ unsigned short AB[65536];   // 128 KB

  int orig = blockIdx.x;
  int bx, by;
  if (EPI == 2 && sym) {
    // 136 upper-tri tiles of 16x16 grid; XCD-chunked bijective (136 = 8*17)
    int x = orig & 7, i = orig >> 3;
    int u = x * 17 + i;
    by = 0; int cum = 0;
    while (cum + (16 - by) <= u) { cum += 16 - by; by++; }
    bx = by + (u - cum);
  } else {
    // XCD x owns row-tiles 2x..2x+1; column-major within strip
    int x = orig & 7, tt = orig >> 3;
    bx = tt >> 1; by = x * 2 + (tt & 1);
  }
  const int row0 = by * 256, col0 = bx * 256;

  const int t = threadIdx.x, l = t & 63, wv = t >> 6;
  const int wr = wv >> 2, wc = wv & 3;           // 2M x 4N wave grid
  const int lr = l & 15;
  const int sA = (l >> 4) ^ ((lr >> 1) & 3);     // swizzled 16B slot for frag reads

  f32x4 acc[8][4];
  #pragma unroll
  for (int i = 0; i < 8; i++)
    #pragma unroll
    for (int j = 0; j < 4; j++) acc[i][j] = (f32x4){0.f, 0.f, 0.f, 0.f};

  const int NT = K >> 6;        // K-tiles of 64
  const int NI = NT >> 1;       // iterations (2 K-tiles each)

  // per-lane staging source bases (pre-swizzled k-slot)
  const int srow  = l >> 2;
  const int sslot = (l & 3) ^ ((l >> 3) & 3);
  const unsigned short* Ap = A  + (size_t)(row0 + srow) * K + sslot * 8;
  const unsigned short* Bp = Bt + (size_t)(col0 + srow) * K + sslot * 8;

  // stage one 16KB region r of tile `tile` (r: 0=Ak0 1=Bk0 2=Ak1 3=Bk1)
  auto STG = [&](int tile, int r) {
    if (tile >= NT) return;
    int buf = tile & 1, ks = r >> 1;
    const unsigned short* src = (r & 1) ? Bp : Ap;
    unsigned short* dst = AB + buf * 32768 + r * 8192;
    size_t koff = (size_t)tile * 64 + ks * 32;
    #pragma unroll
    for (int j = 0; j < 2; j++) {
      int c = wv * 2 + j;
      gload16(src + (size_t)c * 16 * K + koff, dst + c * 512);
    }
  };

#define PHASE(WN, BUF, KS, NH, STILE, SR)                                      \
  {                                                                            \
    if ((WN) == 8) VMW(8); else if ((WN) == 6) VMW(6);                         \
    else if ((WN) == 4) VMW(4); else if ((WN) == 0) VMW(0);                    \
    __builtin_amdgcn_s_barrier();                                              \
    u16x8 af[8], bfv[2];                                                       \
    {                                                                          \
      const unsigned short* ab = &AB[(BUF) * 32768 + (KS) * 16384];            \
      _Pragma("unroll")                                                        \
      for (int mi = 0; mi < 8; mi++)                                           \
        af[mi] = *(const u16x8*)&ab[(wr * 128 + mi * 16 + lr) * 32 + sA * 8];  \
      const unsigned short* bb = ab + 8192;                                    \
      _Pragma("unroll")                                                        \
      for (int nj = 0; nj < 2; nj++)                                           \
        bfv[nj] = *(const u16x8*)&bb[(wc * 64 + (NH) * 32 + nj * 16 + lr) * 32 \
                                     + sA * 8];                                \
    }                                                                          \
    if ((STILE) >= 0) STG(STILE, SR);                                          \
    asm volatile("s_waitcnt lgkmcnt(0)" ::: "memory");                         \
    __builtin_amdgcn_sched_barrier(0);                                         \
    __builtin_amdgcn_s_setprio(1);                                             \
    _Pragma("unroll")                                                          \
    for (int mi = 0; mi < 8; mi++) {                                           \
      acc[mi][(NH) * 2 + 0] = __builtin_amdgcn_mfma_f32_16x16x32_bf16(         \
          __builtin_bit_cast(bf16x8, af[mi]),                                  \
          __builtin_bit_cast(bf16x8, bfv[0]), acc[mi][(NH) * 2 + 0], 0, 0, 0); \
      acc[mi][(NH) * 2 + 1] = __builtin_amdgcn_mfma_f32_16x16x32_bf16(         \
          __builtin_bit_cast(bf16x8, af[mi]),                                  \
          __builtin_bit_cast(bf16x8, bfv[1]), acc[mi][(NH) * 2 + 1], 0, 0, 0); \
    }                                                                          \
    __builtin_amdgcn_s_setprio(0);                                             \
    __builtin_amdgcn_s_barrier();                                              \
  }

  // prologue: 6 halves in canonical order
  STG(0, 0); STG(0, 1); STG(0, 2); STG(0, 3); STG(1, 0); STG(1, 1);

  for (int i = 0; i < NI - 1; ++i) {
    int T = 2 * i;
    PHASE(8, 0, 0, 0, T + 1, 2);
    PHASE(6, 0, 0, 1, T + 1, 3);
    PHASE(-1, 0, 1, 0, T + 2, 0);
    PHASE(-1, 0, 1, 1, T + 2, 1);
    PHASE(8, 1, 0, 0, T + 2, 2);
    PHASE(6, 1, 0, 1, T + 2, 3);
    PHASE(-1, 1, 1, 0, T + 3, 0);
    PHASE(-1, 1, 1, 1, T + 3, 1);
  }
  {
    int T = 2 * (NI - 1);
    PHASE(8, 0, 0, 0, T + 1, 2);
    PHASE(6, 0, 0, 1, T + 1, 3);
    PHASE(-1, 0, 1, 0, -1, 0);
    PHASE(-1, 0, 1, 1, -1, 0);
    PHASE(4, 1, 0, 0, -1, 0);
    PHASE(0, 1, 0, 1, -1, 0);
    PHASE(-1, 1, 1, 0, -1, 0);
    PHASE(-1, 1, 1, 1, -1, 0);
  }
#undef PHASE

  // C/D mapping: col = lane&15, row = (lane>>4)*4 + reg
  const int lcol = l & 15, lrow = (l >> 4) << 2;
  if (EPI == 0) {
    #pragma unroll
    for (int mi = 0; mi < 8; mi++) {
      int rr = row0 + wr * 128 + mi * 16 + lrow;
      #pragma unroll
      for (int nn = 0; nn < 4; nn++) {
        int cc = col0 + wc * 64 + nn * 16 + lcol;
        #pragma unroll
        for (int r = 0; r < 4; r++) {
          float v = acc[mi][nn][r];
          if (rowdiv) v /= rowdiv[rr + r];
          Cb[(size_t)(rr + r) * 4096 + cc] = f2bf(v);
        }
      }
    }
  } else {
    const float* Xf = (const float*)Xv;
    const unsigned short* Xh = (const unsigned short*)Xv;
    float part = 0.f;
    #pragma unroll
    for (int mi = 0; mi < 8; mi++) {
      int rr = row0 + wr * 128 + mi * 16 + lrow;
      #pragma unroll
      for (int nn = 0; nn < 4; nn++) {
        int cc = col0 + wc * 64 + nn * 16 + lcol;
        if (cc < Nc) {
          float cd = coldiv ? coldiv[cc] : 1.f;
          #pragma unroll
          for (int r = 0; r < 4; r++) {
            float v = acc[mi][nn][r];
            if (rowdiv) v /= rowdiv[rr + r];
            v /= cd;
            size_t xi = (size_t)(rr + r) * ldX + cc;
            float xval = XBF ? bf2f(Xh[xi]) : Xf[xi];
            float d = xval - v;
            part = fmaf(d, d, part);
          }
        }
      }
    }
    part = blk_red<false>(part);
    if (t == 0) {
      float wgt = (sym && col0 > row0) ? 2.f : 1.f;
      atomicAdd(slot, part * wgt);
    }
  }
}

// ================== 128-tile bf16 MFMA GEMM (K=64 cases) ==================
// EPI 1: Cf = acc (fp32);  EPI 2: reduce (X-acc/rd/cd)^2;  EPI 3: align+sparsity
template<int EPI, int XBF>
__global__ __launch_bounds__(256)
void bt_mfma_k(const unsigned short* __restrict__ A, const unsigned short* __restrict__ Bt,
               unsigned short* __restrict__ Cb, float* __restrict__ Cf,
               const void* __restrict__ Xv,
               const float* __restrict__ rowdiv, const float* __restrict__ coldiv,
               float* __restrict__ slot, int gx, int Nc, int K, int ldX, int sym)
{
  __shared__ unsigned short AB[3 * 8192];

  int orig = blockIdx.x;
  int x = orig & 7, tt = orig >> 3;
  int bx = tt >> 2;
  int by = x * 4 + (tt & 3);
  const int row0 = by * 128, col0 = bx * 128;

  const int t = threadIdx.x, l = t & 63, wv = t >> 6;
  const int wr = wv >> 1, wc = wv & 1;
  const int lr = l & 15, lkh = (l >> 4) << 3;

  f32x4 acc[4][4];
  #pragma unroll
  for (int i = 0; i < 4; i++)
    #pragma unroll
    for (int j = 0; j < 4; j++) acc[i][j] = (f32x4){0.f, 0.f, 0.f, 0.f};

  const int srow = l >> 2;
  const int sk   = (l & 3) << 3;
  const unsigned short* Ab = A  + (size_t)(row0 + srow) * K + sk;
  const unsigned short* Bb = Bt + (size_t)(col0 + srow) * K + sk;

  const int NT = K >> 5;

  auto STAGE = [&](int kt, int buf) {
    unsigned short* As = AB + buf * 8192;
    unsigned short* Bs = As + 4096;
    int k0 = kt << 5;
    #pragma unroll
    for (int h2 = 0; h2 < 2; h2++) {
      int c = wv * 2 + h2;
      gload16(Ab + (size_t)c * 16 * K + k0, As + c * 512);
      gload16(Bb + (size_t)c * 16 * K + k0, Bs + c * 512);
    }
  };

  STAGE(0, 0);
  if (NT > 1) STAGE(1, 1);
  if (NT > 2) STAGE(2, 2);
  int cur = 0;

  for (int kt = 0; kt < NT; ++kt) {
    int ahead = NT - 1 - kt;
    if (ahead >= 2)      { VMW(8); }
    else if (ahead == 1) { VMW(4); }
    else                 { VMW(0); }
    __builtin_amdgcn_sched_barrier(0);
    __builtin_amdgcn_s_barrier();

    const unsigned short* As = AB + cur * 8192;
    const unsigned short* Bs = As + 4096;
    u16x8 af[4], bfv[4];
    #pragma unroll
    for (int mi = 0; mi < 4; mi++)
      af[mi] = *(const u16x8*)&As[(wr * 64 + mi * 16 + lr) * 32 + lkh];
    #pragma unroll
    for (int ni = 0; ni < 4; ni++)
      bfv[ni] = *(const u16x8*)&Bs[(wc * 64 + ni * 16 + lr) * 32 + lkh];
    #pragma unroll
    for (int mi = 0; mi < 4; mi++)
      #pragma unroll
      for (int ni = 0; ni < 4; ni++)
        acc[mi][ni] = __builtin_amdgcn_mfma_f32_16x16x32_bf16(
            __builtin_bit_cast(bf16x8, af[mi]),
            __builtin_bit_cast(bf16x8, bfv[ni]), acc[mi][ni], 0, 0, 0);

    __builtin_amdgcn_s_barrier();
    if (kt + 3 < NT) STAGE(kt + 3, cur);
    cur = (cur == 2) ? 0 : cur + 1;
  }

  const int lcol = l & 15, lrow = (l >> 4) << 2;
  if (EPI == 1) {
    #pragma unroll
    for (int mi = 0; mi < 4; mi++) {
      int rr = row0 + wr * 64 + mi * 16 + lrow;
      #pragma unroll
      for (int ni = 0; ni < 4; ni++) {
        int cc = col0 + wc * 64 + ni * 16 + lcol;
        #pragma unroll
        for (int r = 0; r < 4; r++)
          Cf[(size_t)(rr + r) * 4096 + cc] = acc[mi][ni][r];
      }
    }
  } else if (EPI == 2) {
    const float* Xf = (const float*)Xv;
    const unsigned short* Xh = (const unsigned short*)Xv;
    float part = 0.f;
    #pragma unroll
    for (int mi = 0; mi < 4; mi++) {
      int rr = row0 + wr * 64 + mi * 16 + lrow;
      #pragma unroll
      for (int ni = 0; ni < 4; ni++) {
        int cc = col0 + wc * 64 + ni * 16 + lcol;
        if (cc < Nc) {
          float cd = coldiv ? coldiv[cc] : 1.f;
          #pragma unroll
          for (int r = 0; r < 4; r++) {
            float v = acc[mi][ni][r];
            if (rowdiv) v /= rowdiv[rr + r];
            v /= cd;
            size_t xi = (size_t)(rr + r) * ldX + cc;
            float xval = XBF ? bf2f(Xh[xi]) : Xf[xi];
            float d = xval - v;
            part = fmaf(d, d, part);
          }
        }
      }
    }
    part = blk_red<false>(part);
    if (t == 0) atomicAdd(slot, part);
  } else { // EPI 3
    const unsigned short* Ph = (const unsigned short*)Xv;
    float a = 0.f, sp = 0.f;
    #pragma unroll
    for (int mi = 0; mi < 4; mi++) {
      int rr = row0 + wr * 64 + mi * 16 + lrow;
      #pragma unroll
      for (int ni = 0; ni < 4; ni++) {
        int cc = col0 + wc * 64 + ni * 16 + lcol;
        #pragma unroll
        for (int r = 0; r < 4; r++) {
          float g = acc[mi][ni][r];
          float p = bf2f(Ph[(size_t)(rr + r) * ldX + cc]);
          float d2 = rowdiv[rr + r] + coldiv[cc] - 2.f * g;
          a = fmaf(p, sqrtf(fmaxf(d2, 1e-12f)), a);
          sp = fmaf(p, logf(p + 1e-10f), sp);
        }
      }
    }
    a = blk_red<false>(a);
    sp = blk_red<false>(sp);
    if (t == 0) { atomicAdd(&slot[ALN], a); atomicAdd(&slot[SPS], sp); }
  }
}

// ============ narrow split-K bf16 MFMA: C[4096][Nc<=128] += A @ Bt^T ============
__global__ __launch_bounds__(256)
void ns_mfma_k(const unsigned short* __restrict__ A, const unsigned short* __restrict__ Bt,
               float* __restrict__ C, int Nc, int K, int KC, int ldC)
{
  __shared__ unsigned short AB[2 * 8192];
  int ks = blockIdx.x & 15, strip = blockIdx.x >> 4;
  const int row0 = strip * 128;
  const int kbase = ks * KC;

  const int t = threadIdx.x, l = t & 63, wv = t >> 6;
  const int wr = wv >> 1, wc = wv & 1;
  const int lr = l & 15, lkh = (l >> 4) << 3;

  f32x4 acc[4][4];
  #pragma unroll
  for (int i = 0; i < 4; i++)
    #pragma unroll
    for (int j = 0; j < 4; j++) acc[i][j] = (f32x4){0.f, 0.f, 0.f, 0.f};

  const int srow = l >> 2;
  const int sk   = (l & 3) << 3;
  const unsigned short* Ab = A  + (size_t)(row0 + srow) * K + kbase + sk;
  const unsigned short* Bb = Bt + (size_t)srow * K + kbase + sk;

  const int NT = KC >> 5;

  auto STAGE = [&](int kt, int buf) {
    unsigned short* As = AB + buf * 8192;
    unsigned short* Bs = As + 4096;
    int k0 = kt << 5;
    #pragma unroll
    for (int h2 = 0; h2 < 2; h2++) {
      int c = wv * 2 + h2;
      gload16(Ab + (size_t)c * 16 * K + k0, As + c * 512);
      gload16(Bb + (size_t)c * 16 * K + k0, Bs + c * 512);
    }
  };

  STAGE(0, 0);
  if (NT > 1) STAGE(1, 1);
  int cur = 0;

  for (int kt = 0; kt < NT; ++kt) {
    if (kt + 1 < NT) { VMW(4); }
    else             { VMW(0); }
    __builtin_amdgcn_sched_barrier(0);
    __builtin_amdgcn_s_barrier();

    const unsigned short* As = AB + cur * 8192;
    const unsigned short* Bs = As + 4096;
    u16x8 af[4], bfv[4];
    #pragma unroll
    for (int mi = 0; mi < 4; mi++)
      af[mi] = *(const u16x8*)&As[(wr * 64 + mi * 16 + lr) * 32 + lkh];
    #pragma unroll
    for (int ni = 0; ni < 4; ni++)
      bfv[ni] = *(const u16x8*)&Bs[(wc * 64 + ni * 16 + lr) * 32 + lkh];
    #pragma unroll
    for (int mi = 0; mi < 4; mi++)
      #pragma unroll
      for (int ni = 0; ni < 4; ni++)
        acc[mi][ni] = __builtin_amdgcn_mfma_f32_16x16x32_bf16(
            __builtin_bit_cast(bf16x8, af[mi]),
            __builtin_bit_cast(bf16x8, bfv[ni]), acc[mi][ni], 0, 0, 0);

    __builtin_amdgcn_s_barrier();
    if (kt + 2 < NT) STAGE(kt + 2, cur);
    cur ^= 1;
  }

  const int lcol = l & 15, lrow = (l >> 4) << 2;
  #pragma unroll
  for (int mi = 0; mi < 4; mi++) {
    int rr = row0 + wr * 64 + mi * 16 + lrow;
    #pragma unroll
    for (int ni = 0; ni < 4; ni++) {
      int cc = wc * 64 + ni * 16 + lcol;
      if (cc < Nc) {
        #pragma unroll
        for (int r = 0; r < 4; r++)
          atomicAdd(&C[(size_t)(rr + r) * ldC + cc], acc[mi][ni][r]);
      }
    }
  }
}

// ---------------- conversion / transpose pre-passes ----------------
__global__ void cvt_k(const float* __restrict__ s, unsigned short* __restrict__ d,
                      int n8, float scale)
{
  int i = blockIdx.x * 256 + threadIdx.x;
  if (i < n8) {
    float4 a = ((const float4*)s)[2 * i], b = ((const float4*)s)[2 * i + 1];
    u16x8 w;
    w[0] = f2bf(a.x * scale); w[1] = f2bf(a.y * scale);
    w[2] = f2bf(a.z * scale); w[3] = f2bf(a.w * scale);
    w[4] = f2bf(b.x * scale); w[5] = f2bf(b.y * scale);
    w[6] = f2bf(b.z * scale); w[7] = f2bf(b.w * scale);
    ((u16x8*)d)[i] = w;
  }
}

// [4096][3000] fp32 -> [4096][3072] bf16 zero-padded
__global__ void cvt_pad_k(const float* __restrict__ s, unsigned short* __restrict__ d)
{
  int i = blockIdx.x * 256 + threadIdx.x;
  int row = i / 384, c8 = (i - row * 384) * 8;
  u16x8 w = (u16x8)0;
  if (c8 < kIN) {
    const float* sp = s + (size_t)row * kIN + c8;
    float4 a = *(const float4*)sp, b = *(const float4*)(sp + 4);
    w[0] = f2bf(a.x); w[1] = f2bf(a.y); w[2] = f2bf(a.z); w[3] = f2bf(a.w);
    w[4] = f2bf(b.x); w[5] = f2bf(b.y); w[6] = f2bf(b.z); w[7] = f2bf(b.w);
  }
  ((u16x8*)d)[i] = w;
}

// [4096][128] fp32 cols 0..63 -> [4096][64] bf16
__global__ void cvt_cols_k(const float* __restrict__ s, unsigned short* __restrict__ d)
{
  int i = blockIdx.x * 256 + threadIdx.x;
  int row = i >> 3, c8 = (i & 7) * 8;
  const float* sp = s + (size_t)row * 128 + c8;
  float4 a = *(const float4*)sp, b = *(const float4*)(sp + 4);
  u16x8 w;
  w[0] = f2bf(a.x); w[1] = f2bf(a.y); w[2] = f2bf(a.z); w[3] = f2bf(a.w);
  w[4] = f2bf(b.x); w[5] = f2bf(b.y); w[6] = f2bf(b.z); w[7] = f2bf(b.w);
  ((u16x8*)d)[i] = w;
}

// transpose+convert: src fp32 [R][C] (ld sld) -> dst bf16 (ld dld), optional relu
template<bool RELU>
__global__ void tr_k(const float* __restrict__ src, unsigned short* __restrict__ dst,
                     int R, int C, int sld, int dld)
{
  __shared__ float tile[32][33];
  int c0 = blockIdx.x * 32, r0 = blockIdx.y * 32;
  int tr_ = threadIdx.x >> 3, tc4 = (threadIdx.x & 7) << 2;
  #pragma unroll
  for (int j = 0; j < 4; j++) {
    int r = r0 + tr_, c = c0 + tc4 + j;
    float v = (r < R && c < C) ? src[(size_t)r * sld + c] : 0.f;
    if (RELU) v = fmaxf(v, 0.f);
    tile[tr_][tc4 + j] = v;
  }
  __syncthreads();
  u16x4 wv;
  #pragma unroll
  for (int j = 0; j < 4; j++) wv[j] = f2bf(tile[tc4 + j][tr_]);
  *(u16x4*)&dst[(size_t)(c0 + tr_) * dld + r0 + tc4] = wv;
}

// ---------------- small fp32 GEMM (64-col weight GEMMs only) ----------------
__global__ __launch_bounds__(256)
void gemm_small_k(const float* __restrict__ A, const float* __restrict__ B,
                  float* __restrict__ C, int M, int Nc, int K,
                  int ldA, int ldB, int ldC)
{
  __shared__ float As[16][68];
  __shared__ float Bs[16][68];
  int tid = threadIdx.x;
  int tx = tid & 15, ty = tid >> 4;
  int row0 = blockIdx.y * 64, col0 = blockIdx.x * 64;
  float acc[4][4] = {};

  for (int k0 = 0; k0 < K; k0 += 16) {
    {
      int m = tid >> 2, kk = (tid & 3) << 2;
      const float* ap = A + (size_t)(row0 + m) * ldA + k0 + kk;
      float4 v = *(const float4*)ap;
      As[kk + 0][m] = v.x; As[kk + 1][m] = v.y; As[kk + 2][m] = v.z; As[kk + 3][m] = v.w;
    }
    {
      int kk = tid >> 4, c = (tid & 15) << 2;
      const float* bp = B + (size_t)(k0 + kk) * ldB + col0 + c;
      #pragma unroll
      for (int i = 0; i < 4; i++)
        Bs[kk][c + i] = (col0 + c + i < Nc) ? bp[i] : 0.f;
    }
    __syncthreads();
    #pragma unroll
    for (int kk = 0; kk < 16; kk++) {
      float4 a4 = *(const float4*)&As[kk][ty << 2];
      float4 b4 = *(const float4*)&Bs[kk][tx << 2];
      float av[4] = {a4.x, a4.y, a4.z, a4.w};
      float bv[4] = {b4.x, b4.y, b4.z, b4.w};
      #pragma unroll
      for (int i = 0; i < 4; i++)
        #pragma unroll
        for (int j = 0; j < 4; j++)
          acc[i][j] = fmaf(av[i], bv[j], acc[i][j]);
    }
    __syncthreads();
  }
  #pragma unroll
  for (int i = 0; i < 4; i++) {
    int r = row0 + (ty << 2) + i;
    #pragma unroll
    for (int j = 0; j < 4; j++) {
      int c = col0 + (tx << 2) + j;
      if (c < Nc) C[(size_t)r * ldC + c] = acc[i][j];
    }
  }
}

// ---------------- fused Sinkhorn passes ----------------
__global__ __launch_bounds__(256)
void sink_k(float* __restrict__ P, unsigned short* __restrict__ Pb,
            const float* __restrict__ cs_in, float* __restrict__ cs_out,
            float* __restrict__ rs, int mode)
{
  int tid = threadIdx.x;
  int r0 = blockIdx.x * 8;
  float csl[16] = {};
  float cdiv[16];
  if (mode != 0) {
    #pragma unroll
    for (int t = 0; t < 4; t++) {
      float4 c4 = ((const float4*)cs_in)[tid + t * 256];
      cdiv[4 * t + 0] = 1.f / (4096.f * c4.x);
      cdiv[4 * t + 1] = 1.f / (4096.f * c4.y);
      cdiv[4 * t + 2] = 1.f / (4096.f * c4.z);
      cdiv[4 * t + 3] = 1.f / (4096.f * c4.w);
    }
  }
  for (int rr = 0; rr < 8; rr++) {
    int row = r0 + rr;
    float4* prow = (float4*)(P + (size_t)row * 4096);
    float4 r[4];
    #pragma unroll
    for (int t = 0; t < 4; t++) r[t] = prow[tid + t * 256];

    if (mode == 0) {
      float m = -3.4e38f;
      #pragma unroll
      for (int t = 0; t < 4; t++)
        m = fmaxf(m, fmaxf(fmaxf(r[t].x, r[t].y), fmaxf(r[t].z, r[t].w)));
      m = blk_red<true>(m);
      float s = 0.f;
      #pragma unroll
      for (int t = 0; t < 4; t++) {
        r[t].x = expf(r[t].x - m); r[t].y = expf(r[t].y - m);
        r[t].z = expf(r[t].z - m); r[t].w = expf(r[t].w - m);
        s += r[t].x + r[t].y + r[t].z + r[t].w;
      }
      s = blk_red<false>(s);
      float f = 1.f / (s * 4096.f);
      #pragma unroll
      for (int t = 0; t < 4; t++) {
        r[t].x *= f; r[t].y *= f; r[t].z *= f; r[t].w *= f;
        prow[tid + t * 256] = r[t];
        csl[4 * t + 0] += r[t].x; csl[4 * t + 1] += r[t].y;
        csl[4 * t + 2] += r[t].z; csl[4 * t + 3] += r[t].w;
      }
    } else {
      float s = 0.f;
      #pragma unroll
      for (int t = 0; t < 4; t++) {
        r[t].x *= cdiv[4 * t + 0]; r[t].y *= cdiv[4 * t + 1];
        r[t].z *= cdiv[4 * t + 2]; r[t].w *= cdiv[4 * t + 3];
        s += r[t].x + r[t].y + r[t].z + r[t].w;
      }
      s = blk_red<false>(s);
      if (mode == 1) {
        float f = 1.f / (4096.f * s);
        #pragma unroll
        for (int t = 0; t < 4; t++) {
          r[t].x *= f; r[t].y *= f; r[t].z *= f; r[t].w *= f;
          prow[tid + t * 256] = r[t];
          csl[4 * t + 0] += r[t].x; csl[4 * t + 1] += r[t].y;
          csl[4 * t + 2] += r[t].z; csl[4 * t + 3] += r[t].w;
        }
      } else {
        if (tid == 0) rs[row] = s;
        #pragma unroll
        for (int t = 0; t < 4; t++) {
          prow[tid + t * 256] = r[t];
          u16x4 w;
          w[0] = f2bf(r[t].x); w[1] = f2bf(r[t].y);
          w[2] = f2bf(r[t].z); w[3] = f2bf(r[t].w);
          *(u16x4*)&Pb[(size_t)row * 4096 + 4 * (tid + t * 256)] = w;
          csl[4 * t + 0] += r[t].x; csl[4 * t + 1] += r[t].y;
          csl[4 * t + 2] += r[t].z; csl[4 * t + 3] += r[t].w;
        }
      }
    }
  }
  #pragma unroll
  for (int t = 0; t < 4; t++) {
    int j = 4 * (tid + t * 256);
    atomicAdd(&cs_out[j + 0], csl[4 * t + 0]);
    atomicAdd(&cs_out[j + 1], csl[4 * t + 1]);
    atomicAdd(&cs_out[j + 2], csl[4 * t + 2]);
    atomicAdd(&cs_out[j + 3], csl[4 * t + 3]);
  }
}

__global__ __launch_bounds__(256)
void rowsum_k(const float* __restrict__ Pm, float* __restrict__ vec)
{
  int i = blockIdx.x, tid = threadIdx.x;
  const float4* prow = (const float4*)(Pm + (size_t)i * kN);
  float s = 0.f;
  #pragma unroll
  for (int t = 0; t < 4; t++) {
    float4 r = prow[tid + t * 256];
    s += r.x + r.y + r.z + r.w;
  }
  s = blk_red<false>(s);
  if (tid == 0) vec[i] = s;
}

__global__ void relu_k(const float* __restrict__ in, float* __restrict__ out, int n)
{
  int i = blockIdx.x * blockDim.x + threadIdx.x;
  if (i < n) out[i] = fmaxf(in[i], 0.f);
}

__global__ void gather_k(float* __restrict__ XP, const int* __restrict__ perm)
{
  int gid = blockIdx.x * 256 + threadIdx.x;
  int i = gid >> 6, j = gid & 63;
  XP[(size_t)i * 128 + 64 + j] = XP[(size_t)perm[i] * 128 + j];
}

__global__ void sqnorm_k(const float* __restrict__ H, int ld, float* __restrict__ outv)
{
  int gid = blockIdx.x * 256 + threadIdx.x;
  int row = gid >> 6, j = gid & 63;
  float v = H[(size_t)row * ld + j];
  float p = wave_red_sum(v * v);
  if (j == 0) outv[row] = p;
}

__global__ void readout_k(const float* __restrict__ vs2, const float* __restrict__ mrs,
                          float* __restrict__ g2)
{
  int q = blockIdx.x, j = threadIdx.x;
  float v = vs2[(size_t)q * 64 + j] / mrs[q >> 1];
  float p = v * v;
  #pragma unroll
  for (int s = 1; s < 64; s <<= 1) p += __shfl_xor(p, s, 64);
  float nrm = sqrtf(p);
  v = v / fmaxf(nrm, 1e-12f);
  g2[(size_t)q * 64 + j] = 1.f / (1.f + expf(-v));
}

__device__ __forceinline__ float bce_term(float x, float y) {
  return fmaxf(x, 0.f) - x * y + log1pf(expf(-fabsf(x)));
}

__global__ void disc_k(const float* __restrict__ G2, const float* __restrict__ W2,
                       const float* __restrict__ lab, const float* __restrict__ bptr,
                       float* __restrict__ acc)
{
  int i = blockIdx.x, j = threadIdx.x;
  float gj  = G2[(size_t)(2 * i) * 64 + j];
  float gaj = G2[(size_t)(2 * i + 1) * 64 + j];
  float hw  = W2[(size_t)(2 * i) * 64 + j];
  float haw = W2[(size_t)(2 * i + 1) * 64 + j];
  float s1 = hw * gj, s2 = haw * gj, s1a = haw * gaj, s2a = hw * gaj;
  #pragma unroll
  for (int s = 1; s < 64; s <<= 1) {
    s1  += __shfl_xor(s1, s, 64);
    s2  += __shfl_xor(s2, s, 64);
    s1a += __shfl_xor(s1a, s, 64);
    s2a += __shfl_xor(s2a, s, 64);
  }
  if (j == 0) {
    float b = bptr[0];
    float y0 = lab[i * 2 + 0], y1 = lab[i * 2 + 1];
    float t = bce_term(s1 + b, y0) + bce_term(s2 + b, y1)
            + bce_term(s1a + b, y0) + bce_term(s2a + b, y1);
    atomicAdd(&acc[SL], t);
  }
}

__global__ __launch_bounds__(256)
void finalize_k(const float* __restrict__ acc, const float* __restrict__ cs,
                float* __restrict__ out)
{
  int tid = threadIdx.x;
  float invm2 = 1.f / (float)kN;
  float t = 0.f;
  for (int j = tid; j < kN; j += 256) {
    float q = cs[j];
    t += q * (logf(q) - invm2);
  }
  t = blk_red<false>(t);
  if (tid == 0) {
    float kld_pq = t * invm2;
    float kld_pp = invm2 * (logf(invm2) - invm2);
    out[0] = acc[SL] / (2.f * (float)kN);
    out[1] = acc[FEAT] / ((float)kN * (float)kIN);
    out[2] = acc[ALN];
    out[3] = (acc[FXA] + acc[FXB]) / ((float)kN * (float)kIN);
    out[4] = sqrtf(acc[SM1]) / (float)kN + sqrtf(acc[SM2]) / (float)kN;
    out[5] = (kld_pq - kld_pp) * (float)kN;
    out[6] = -acc[SPS];
  }
}

extern "C" void kernel_launch(void* const* d_in, const int* in_sizes, int n_in,
                              void* d_out, int out_size, void* d_ws, size_t ws_size,
                              hipStream_t stream)
{
  (void)in_sizes; (void)n_in; (void)out_size; (void)ws_size;
  const float* feat  = (const float*)d_in[0];
  const float* adjs  = (const float*)d_in[1];
  const float* gmask = (const float*)d_in[2];
  const float* labs  = (const float*)d_in[3];
  const float* dists = (const float*)d_in[4];
  const int*   perms = (const int*)d_in[5];
  const float* encW  = (const float*)d_in[6];
  const float* decW  = (const float*)d_in[7];
  const float* MsW   = (const float*)d_in[8];
  const float* discW = (const float*)d_in[9];
  const float* discb = (const float*)d_in[10];
  float* out = (float*)d_out;

  const size_t SZNN = (size_t)kN * kN;

  char* cur = (char*)d_ws;
  auto alloc = [&](size_t bytes) {
    char* p = cur;
    cur += (bytes + 255) & ~(size_t)255;
    return p;
  };
  float* P            = (float*)alloc(SZNN * 4);          // fp32 P; later reused for Tb
  unsigned short* Pb  = (unsigned short*)alloc(SZNN * 2);
  unsigned short* PbT = (unsigned short*)alloc(SZNN * 2);
  unsigned short* Db  = (unsigned short*)alloc(SZNN * 2);
  unsigned short* ajb = (unsigned short*)alloc(SZNN * 2); // adj/msk bf16; later ftb
  unsigned short* xb  = (unsigned short*)alloc((size_t)kN * kINp * 2);
  unsigned short* dWtb= (unsigned short*)alloc((size_t)kINp * kLAT * 2);
  unsigned short* ahb = (unsigned short*)alloc((size_t)kN * kLAT * 2);
  unsigned short* encWtp = (unsigned short*)alloc((size_t)128 * kINp * 2);
  unsigned short* XPt = (unsigned short*)alloc((size_t)128 * kN * 2);
  unsigned short* hbTp= (unsigned short*)alloc((size_t)128 * kN * 2);
  unsigned short* HRt = (unsigned short*)alloc((size_t)128 * kN * 2);
  unsigned short* smb = (unsigned short*)alloc((size_t)kN * kLAT * 2);
  unsigned short* tmb = (unsigned short*)alloc((size_t)kN * kLAT * 2);
  unsigned short* h0b = (unsigned short*)alloc((size_t)kN * kLAT * 2);
  unsigned short* h1b = (unsigned short*)alloc((size_t)kN * kLAT * 2);
  float* XP  = (float*)alloc((size_t)kN * 128 * 4);
  float* HH0 = (float*)alloc((size_t)kN * 128 * 4);
  float* HH1 = (float*)alloc((size_t)kN * 128 * 4);
  float* HR  = (float*)alloc((size_t)kN * 128 * 4);
  float* VS  = (float*)alloc((size_t)kN * 128 * 4);
  float* G2  = (float*)alloc((size_t)kN * 128 * 4);
  float* W2  = (float*)alloc((size_t)kN * 128 * 4);
  float* SM_ = (float*)alloc((size_t)kN * kLAT * 4);
  float* TM_ = (float*)alloc((size_t)kN * kLAT * 4);
  float* ah  = (float*)alloc((size_t)kN * kLAT * 4);
  float* sns = (float*)alloc(kN * 4);
  float* snt = (float*)alloc(kN * 4);
  float* rs  = (float*)alloc(kN * 4);
  float* cs  = (float*)alloc(kN * 4);
  float* csA = (float*)alloc(kN * 4);
  float* csB = (float*)alloc(kN * 4);
  float* mrs = (float*)alloc(kN * 4);
  float* acc = (float*)alloc(NSLOT * 4);

  unsigned short* Tb  = (unsigned short*)P;     // alias: fp32 P dead before Tb written
  unsigned short* ftb = ajb;                    // alias: adj/msk bf16 dead after slices

  hipMemsetAsync(acc, 0, NSLOT * sizeof(float), stream);

  // ---------------- per-slice losses ----------------
  for (int k = 0; k < 2; k++) {
    const float* x    = feat  + (size_t)k * kN * kIN;
    const float* adj  = adjs  + (size_t)k * SZNN;
    const float* msk  = gmask + (size_t)k * SZNN;
    const float* lab  = labs  + (size_t)k * kN * 2;
    const int*   perm = perms + (size_t)k * kN;
    const float* eW   = encW  + (size_t)k * kIN * kLAT;
    const float* dW   = decW  + (size_t)k * kLAT * kIN;
    float* HHk = (k == 0) ? HH0 : HH1;

    cvt_pad_k<<<6144, 256, 0, stream>>>(x, xb);
    hipMemsetAsync(encWtp, 0, (size_t)128 * kINp * 2, stream);
    tr_k<false><<<dim3(2, (kIN + 31) / 32), 256, 0, stream>>>(eW, encWtp, kIN, kLAT, kLAT, kINp);
    hipMemsetAsync(XP, 0, (size_t)kN * 128 * 4, stream);
    ns_mfma_k<<<512, 256, 0, stream>>>(xb, encWtp, XP, kLAT, kINp, kINp / 16, 128);
    gather_k<<<kN * 64 / 256, 256, 0, stream>>>(XP, perm);
    tr_k<false><<<dim3(4, 128), 256, 0, stream>>>(XP, XPt, kN, 128, 128, kN);
    cvt_k<<<(int)(SZNN / 8 / 256), 256, 0, stream>>>(adj, ajb, (int)(SZNN / 8), 1.f);
    hipMemsetAsync(HHk, 0, (size_t)kN * 128 * 4, stream);
    ns_mfma_k<<<512, 256, 0, stream>>>(ajb, XPt, HHk, 128, kN, kN / 16, 128);
    hipMemsetAsync(hbTp, 0, (size_t)128 * kN * 2, stream);
    tr_k<false><<<dim3(2, 128), 256, 0, stream>>>(HHk, hbTp, kN, kLAT, 128, kN);
    hipMemsetAsync(ah, 0, (size_t)kN * kLAT * 4, stream);
    ns_mfma_k<<<512, 256, 0, stream>>>(ajb, hbTp, ah, kLAT, kN, kN / 16, kLAT);
    cvt_k<<<128, 256, 0, stream>>>(ah, ahb, kN * kLAT / 8, 1.f);
    tr_k<false><<<dim3(kINp / 32, 2), 256, 0, stream>>>(dW, dWtb, kLAT, kIN, kIN, kLAT);
    bt_mfma_k<2, 1><<<(kINp / 128) * 32, 256, 0, stream>>>(
        ahb, dWtb, nullptr, nullptr, xb, nullptr, nullptr, &acc[FEAT],
        kINp / 128, kIN, kLAT, kINp, 0);
    relu_k<<<kN * 128 / 256, 256, 0, stream>>>(HHk, HR, kN * 128);
    tr_k<true><<<dim3(4, 128), 256, 0, stream>>>(HHk, HRt, kN, 128, 128, kN);
    cvt_k<<<(int)(SZNN / 8 / 256), 256, 0, stream>>>(msk, ajb, (int)(SZNN / 8), 1.f);
    hipMemsetAsync(VS, 0, (size_t)kN * 128 * 4, stream);
    ns_mfma_k<<<512, 256, 0, stream>>>(ajb, HRt, VS, 128, kN, kN / 16, 128);
    rowsum_k<<<kN, 256, 0, stream>>>(msk, mrs);
    readout_k<<<2 * kN, 64, 0, stream>>>(VS, mrs, G2);
    gemm_small_k<<<dim3(1, 128), 256, 0, stream>>>(HR, discW, W2, 2 * kN, kLAT, kLAT,
                                                   kLAT, kLAT, kLAT);
    disc_k<<<kN, 64, 0, stream>>>(G2, W2, lab, discb, acc);
  }

  // ---------------- alignment losses ----------------
  const float* f0 = feat;
  const float* f1 = feat + (size_t)kN * kIN;
  const float* D0 = dists;
  const float* D1 = dists + SZNN;

  gemm_small_k<<<dim3(1, 64), 256, 0, stream>>>(HH0, MsW, SM_, kN, kLAT, kLAT, 128, kLAT, kLAT);
  gemm_small_k<<<dim3(1, 64), 256, 0, stream>>>(HH1, MsW, TM_, kN, kLAT, kLAT, 128, kLAT, kLAT);
  cvt_k<<<128, 256, 0, stream>>>(SM_, smb, kN * kLAT / 8, 0.125f);
  cvt_k<<<128, 256, 0, stream>>>(TM_, tmb, kN * kLAT / 8, 1.f);
  // P = srcM @ tgtM^T / 8  (128-tile MFMA, fp32 store)
  bt_mfma_k<1, 0><<<1024, 256, 0, stream>>>(smb, tmb, nullptr, P, nullptr, nullptr, nullptr,
                                            nullptr, 32, kN, kLAT, 0, 0);

  // fused sinkhorn: softmax + 3 iters + final marginals + bf16 P, 4 passes
  hipMemsetAsync(csA, 0, kN * 4, stream);
  sink_k<<<512, 256, 0, stream>>>(P, nullptr, nullptr, csA, nullptr, 0);
  hipMemsetAsync(csB, 0, kN * 4, stream);
  sink_k<<<512, 256, 0, stream>>>(P, nullptr, csA, csB, nullptr, 1);
  hipMemsetAsync(csA, 0, kN * 4, stream);
  sink_k<<<512, 256, 0, stream>>>(P, nullptr, csB, csA, nullptr, 1);
  hipMemsetAsync(cs, 0, kN * 4, stream);
  sink_k<<<512, 256, 0, stream>>>(P, Pb, csA, cs, rs, 2);

  // PbT = bf16(P^T) — last read of fp32 P
  tr_k<false><<<dim3(kN / 32, kN / 32), 256, 0, stream>>>(P, PbT, kN, kN, kN, kN);

  // align + sparsity: h0@h1^T (128-tile MFMA, EPI3)
  cvt_cols_k<<<128, 256, 0, stream>>>(HH0, h0b);
  cvt_cols_k<<<128, 256, 0, stream>>>(HH1, h1b);
  sqnorm_k<<<kN * 64 / 256, 256, 0, stream>>>(HH0, 128, sns);
  sqnorm_k<<<kN * 64 / 256, 256, 0, stream>>>(HH1, 128, snt);
  bt_mfma_k<3, 1><<<1024, 256, 0, stream>>>(h0b, h1b, nullptr, nullptr, Pb, sns, snt, acc,
                                            32, kN, kLAT, kN, 0);

  // loss_align_fix (8-phase 256-tile)
  tr_k<false><<<dim3(kINp / 32, kN / 32), 256, 0, stream>>>(f1, ftb, kN, kIN, kIN, kN);
  g8_mfma_k<2, 0><<<192, 512, 0, stream>>>(Pb, ftb, nullptr, f0, rs, nullptr,
                                           &acc[FXA], kIN, kN, kIN, 0);
  tr_k<false><<<dim3(kINp / 32, kN / 32), 256, 0, stream>>>(f0, ftb, kN, kIN, kIN, kN);
  g8_mfma_k<2, 0><<<192, 512, 0, stream>>>(PbT, ftb, nullptr, f1, cs, nullptr,
                                           &acc[FXB], kIN, kN, kIN, 0);

  // loss_maintain 1: Tb = (P@D1)/rs ; SM1 = sum((D0 - (Tb@P^T)/rs)^2) sym
  cvt_k<<<(int)(SZNN / 8 / 256), 256, 0, stream>>>(D1, Db, (int)(SZNN / 8), 1.f);
  g8_mfma_k<0, 0><<<256, 512, 0, stream>>>(Pb, Db, Tb, nullptr, rs, nullptr,
                                           nullptr, kN, kN, 0, 0);
  g8_mfma_k<2, 0><<<136, 512, 0, stream>>>(Tb, Pb, nullptr, D0, nullptr, rs,
                                           &acc[SM1], kN, kN, kN, 1);
  // loss_maintain 2: Tb = (P^T@D0)/cs ; SM2 = sum((D1 - (Tb@P)/cs)^2) sym
  cvt_k<<<(int)(SZNN / 8 / 256), 256, 0, stream>>>(D0, Db, (int)(SZNN / 8), 1.f);
  g8_mfma_k<0, 0><<<256, 512, 0, stream>>>(PbT, Db, Tb, nullptr, cs, nullptr,
                                           nullptr, kN, kN, 0, 0);
  g8_mfma_k<2, 0><<<136, 512, 0, stream>>>(Tb, PbT, nullptr, D1, nullptr, cs,
                                           &acc[SM2], kN, kN, kN, 1);

  finalize_k<<<1, 256, 0, stream>>>(acc, cs, out);
}

// Round 7
// 2060.949 us; speedup vs baseline: 1.0200x; 1.0200x over previous
//
#include <hip/hip_runtime.h>
#include <cmath>

// Problem constants
constexpr int kN   = 4096;
constexpr int kIN  = 3000;
constexpr int kINp = 3072;   // kIN padded to 128-multiple
constexpr int kLAT = 64;

enum { SL = 0, FEAT, ALN, FXA, FXB, SM1, SM2, SPS, NSLOT };

typedef __bf16 bf16x8 __attribute__((ext_vector_type(8)));
typedef float f32x4 __attribute__((ext_vector_type(4)));
typedef unsigned short u16x8 __attribute__((ext_vector_type(8)));
typedef unsigned short u16x4 __attribute__((ext_vector_type(4)));

// ---------------- reduction helpers ----------------
template<bool IS_MAX>
__device__ __forceinline__ float blk_red(float v) {
  __shared__ float buf[8];
  #pragma unroll
  for (int s = 32; s > 0; s >>= 1) {
    float o = __shfl_down(v, s, 64);
    v = IS_MAX ? fmaxf(v, o) : (v + o);
  }
  int lane = threadIdx.x & 63, wv = threadIdx.x >> 6, nw = blockDim.x >> 6;
  __syncthreads();
  if (lane == 0) buf[wv] = v;
  __syncthreads();
  float r = buf[0];
  for (int i = 1; i < nw; i++) r = IS_MAX ? fmaxf(r, buf[i]) : (r + buf[i]);
  return r;
}

__device__ __forceinline__ float wave_red_sum(float v) {
  #pragma unroll
  for (int s = 32; s > 0; s >>= 1) v += __shfl_down(v, s, 64);
  return v;
}

// fp32 -> bf16 RNE ; bf16 -> fp32
__device__ __forceinline__ unsigned short f2bf(float f) {
  unsigned u = __builtin_bit_cast(unsigned, f);
  u += 0x7fffu + ((u >> 16) & 1u);
  return (unsigned short)(u >> 16);
}
__device__ __forceinline__ float bf2f(unsigned short h) {
  return __builtin_bit_cast(float, (unsigned)h << 16);
}

// async global->LDS, 16B per lane
__device__ __forceinline__ void gload16(const unsigned short* g, unsigned short* l) {
  __builtin_amdgcn_global_load_lds(
      (const __attribute__((address_space(1))) unsigned int*)g,
      (__attribute__((address_space(3))) unsigned int*)l, 16, 0, 0);
}

#define VMW(n) asm volatile("s_waitcnt vmcnt(" #n ")" ::: "memory")

// ============================================================================
// 256x256-tile 8-phase bf16 MFMA GEMM: Cb = bf16((A @ Bt^T)/rowdiv). K mult 128.
// Dense only, grid = 256 (16x16 tiles), 512 thr = 8 waves (2M x 4N).
// af-reuse: PH_A loads af[8]+bfv01 (10 b128), PH_B loads bfv23 only (2 b128)
// -> 48 ds_read_b128 per wave per iter (2 K-tiles of 64).
// Counted waits: vmcnt(8) at even phases; last iter peeled {8,8,4,0}.
// ============================================================================
__global__ __launch_bounds__(512, 2)
void g8_mfma_k(const unsigned short* __restrict__ A, const unsigned short* __restrict__ Bt,
               unsigned short* __restrict__ Cb, const float* __restrict__ rowdiv, int K)
{
  __shared__ unsigned short AB[65536];   // 128 KB

  int orig = blockIdx.x;
  int x = orig & 7, tt = orig >> 3;
  int bx = tt >> 1, by = x * 2 + (tt & 1);   // XCD x owns row-tiles 2x..2x+1
  const int row0 = by * 256, col0 = bx * 256;

  const int t = threadIdx.x, l = t & 63, wv = t >> 6;
  const int wr = wv >> 2, wc = wv & 3;           // 2M x 4N wave grid
  const int lr = l & 15;
  const int sA = (l >> 4) ^ ((lr >> 1) & 3);     // swizzled 16B slot for frag reads

  f32x4 acc[8][4];
  #pragma unroll
  for (int i = 0; i < 8; i++)
    #pragma unroll
    for (int j = 0; j < 4; j++) acc[i][j] = (f32x4){0.f, 0.f, 0.f, 0.f};

  const int NT = K >> 6;        // K-tiles of 64
  const int NI = NT >> 1;       // iterations (2 K-tiles each)

  // per-lane staging source bases (pre-swizzled k-slot; rule #21 both-sides)
  const int srow  = l >> 2;
  const int sslot = (l & 3) ^ ((l >> 3) & 3);
  const unsigned short* Ap = A  + (size_t)(row0 + srow) * K + sslot * 8;
  const unsigned short* Bp = Bt + (size_t)(col0 + srow) * K + sslot * 8;

  // stage one 16KB region r of tile `tile` (r: 0=Ak0 1=Bk0 2=Ak1 3=Bk1)
  auto STG = [&](int tile, int r) {
    if (tile >= NT) return;
    int buf = tile & 1, ks = r >> 1;
    const unsigned short* src = (r & 1) ? Bp : Ap;
    unsigned short* dst = AB + buf * 32768 + r * 8192;
    size_t koff = (size_t)tile * 64 + ks * 32;
    #pragma unroll
    for (int j = 0; j < 2; j++) {
      int c = wv * 2 + j;
      gload16(src + (size_t)c * 16 * K + koff, dst + c * 512);
    }
  };

  u16x8 af[8], bfv[2];

#define MFMA16(AV, BV, ACC) \
  ACC = __builtin_amdgcn_mfma_f32_16x16x32_bf16( \
      __builtin_bit_cast(bf16x8, AV), __builtin_bit_cast(bf16x8, BV), ACC, 0, 0, 0)

#define PH_A(WN, BUF, KS, STILE, SR)                                           \
  {                                                                            \
    if ((WN) == 8) VMW(8); else if ((WN) == 4) VMW(4);                         \
    else if ((WN) == 0) VMW(0);                                                \
    __builtin_amdgcn_s_barrier();                                              \
    {                                                                          \
      const unsigned short* ab = &AB[(BUF) * 32768 + (KS) * 16384];            \
      _Pragma("unroll")                                                        \
      for (int mi = 0; mi < 8; mi++)                                           \
        af[mi] = *(const u16x8*)&ab[(wr * 128 + mi * 16 + lr) * 32 + sA * 8];  \
      const unsigned short* bb = ab + 8192;                                    \
      bfv[0] = *(const u16x8*)&bb[(wc * 64 +  0 + lr) * 32 + sA * 8];          \
      bfv[1] = *(const u16x8*)&bb[(wc * 64 + 16 + lr) * 32 + sA * 8];          \
    }                                                                          \
    if ((STILE) >= 0) STG(STILE, SR);                                          \
    asm volatile("s_waitcnt lgkmcnt(0)" ::: "memory");                         \
    __builtin_amdgcn_sched_barrier(0);                                         \
    __builtin_amdgcn_s_setprio(1);                                             \
    _Pragma("unroll")                                                          \
    for (int mi = 0; mi < 8; mi++) {                                           \
      MFMA16(af[mi], bfv[0], acc[mi][0]);                                      \
      MFMA16(af[mi], bfv[1], acc[mi][1]);                                      \
    }                                                                          \
    __builtin_amdgcn_s_setprio(0);                                             \
    __builtin_amdgcn_s_barrier();                                              \
  }

#define PH_B(BUF, KS, STILE, SR)                                               \
  {                                                                            \
    __builtin_amdgcn_s_barrier();                                              \
    {                                                                          \
      const unsigned short* bb = &AB[(BUF) * 32768 + (KS) * 16384 + 8192];     \
      bfv[0] = *(const u16x8*)&bb[(wc * 64 + 32 + lr) * 32 + sA * 8];          \
      bfv[1] = *(const u16x8*)&bb[(wc * 64 + 48 + lr) * 32 + sA * 8];          \
    }                                                                          \
    if ((STILE) >= 0) STG(STILE, SR);                                          \
    asm volatile("s_waitcnt lgkmcnt(0)" ::: "memory");                         \
    __builtin_amdgcn_sched_barrier(0);                                         \
    __builtin_amdgcn_s_setprio(1);                                             \
    _Pragma("unroll")                                                          \
    for (int mi = 0; mi < 8; mi++) {                                           \
      MFMA16(af[mi], bfv[0], acc[mi][2]);                                      \
      MFMA16(af[mi], bfv[1], acc[mi][3]);                                      \
    }                                                                          \
    __builtin_amdgcn_s_setprio(0);                                             \
    __builtin_amdgcn_s_barrier();                                              \
  }

  // prologue: 6 regions in canonical order
  STG(0, 0); STG(0, 1); STG(0, 2); STG(0, 3); STG(1, 0); STG(1, 1);

  for (int i = 0; i < NI - 1; ++i) {
    int T = 2 * i;
    PH_A(8, 0, 0, T + 1, 2);
    PH_B(   0, 0, T + 1, 3);
    PH_A(8, 0, 1, T + 2, 0);
    PH_B(   0, 1, T + 2, 1);
    PH_A(8, 1, 0, T + 2, 2);
    PH_B(   1, 0, T + 2, 3);
    PH_A(8, 1, 1, T + 3, 0);
    PH_B(   1, 1, T + 3, 1);
  }
  {
    int T = 2 * (NI - 1);
    PH_A(8, 0, 0, T + 1, 2);
    PH_B(   0, 0, T + 1, 3);
    PH_A(8, 0, 1, -1, 0);
    PH_B(   0, 1, -1, 0);
    PH_A(4, 1, 0, -1, 0);
    PH_B(   1, 0, -1, 0);
    PH_A(0, 1, 1, -1, 0);
    PH_B(   1, 1, -1, 0);
  }
#undef PH_A
#undef PH_B
#undef MFMA16

  // C/D mapping: col = lane&15, row = (lane>>4)*4 + reg
  const int lcol = l & 15, lrow = (l >> 4) << 2;
  #pragma unroll
  for (int mi = 0; mi < 8; mi++) {
    int rr = row0 + wr * 128 + mi * 16 + lrow;
    #pragma unroll
    for (int nn = 0; nn < 4; nn++) {
      int cc = col0 + wc * 64 + nn * 16 + lcol;
      #pragma unroll
      for (int r = 0; r < 4; r++) {
        float v = acc[mi][nn][r];
        if (rowdiv) v /= rowdiv[rr + r];
        Cb[(size_t)(rr + r) * 4096 + cc] = f2bf(v);
      }
    }
  }
}

// ================== 128-tile bf16 MFMA GEMM: C = A @ Bt^T ==================
// 3-deep pipeline, counted vmcnt. Dense strip decode or sym triangular (528).
// EPI 1: Cf = acc (fp32);  EPI 2: slot += wgt*sum (X - acc/rd/cd)^2 (X fp32/bf16)
// EPI 3: align+sparsity epilogue
template<int EPI, int XBF>
__global__ __launch_bounds__(256)
void bt_mfma_k(const unsigned short* __restrict__ A, const unsigned short* __restrict__ Bt,
               unsigned short* __restrict__ Cb, float* __restrict__ Cf,
               const void* __restrict__ Xv,
               const float* __restrict__ rowdiv, const float* __restrict__ coldiv,
               float* __restrict__ slot, int gx, int Nc, int K, int ldX, int sym)
{
  __shared__ unsigned short AB[3 * 8192];

  int orig = blockIdx.x;
  int bx, by;
  if (EPI == 2 && sym) {
    // 528 upper-tri tiles of a 32x32 grid; XCD-chunked bijective (528 = 8*66)
    int x = orig & 7, i = orig >> 3;
    int u = x * 66 + i;
    float disc = 4225.f - 8.f * (float)u;
    by = (int)((65.f - sqrtf(fmaxf(disc, 0.f))) * 0.5f);
    while (by > 0 && 32 * by - by * (by - 1) / 2 > u) by--;
    while (32 * (by + 1) - (by + 1) * by / 2 <= u) by++;
    bx = by + (u - (32 * by - by * (by - 1) / 2));
  } else {
    int x = orig & 7, tt = orig >> 3;
    bx = tt >> 2;
    by = x * 4 + (tt & 3);
  }
  const int row0 = by * 128, col0 = bx * 128;

  const int t = threadIdx.x, l = t & 63, wv = t >> 6;
  const int wr = wv >> 1, wc = wv & 1;
  const int lr = l & 15, lkh = (l >> 4) << 3;

  f32x4 acc[4][4];
  #pragma unroll
  for (int i = 0; i < 4; i++)
    #pragma unroll
    for (int j = 0; j < 4; j++) acc[i][j] = (f32x4){0.f, 0.f, 0.f, 0.f};

  const int srow = l >> 2;
  const int sk   = (l & 3) << 3;
  const unsigned short* Ab = A  + (size_t)(row0 + srow) * K + sk;
  const unsigned short* Bb = Bt + (size_t)(col0 + srow) * K + sk;

  const int NT = K >> 5;

  auto STAGE = [&](int kt, int buf) {
    unsigned short* As = AB + buf * 8192;
    unsigned short* Bs = As + 4096;
    int k0 = kt << 5;
    #pragma unroll
    for (int h2 = 0; h2 < 2; h2++) {
      int c = wv * 2 + h2;
      gload16(Ab + (size_t)c * 16 * K + k0, As + c * 512);
      gload16(Bb + (size_t)c * 16 * K + k0, Bs + c * 512);
    }
  };

  STAGE(0, 0);
  if (NT > 1) STAGE(1, 1);
  if (NT > 2) STAGE(2, 2);
  int cur = 0;

  for (int kt = 0; kt < NT; ++kt) {
    int ahead = NT - 1 - kt;
    if (ahead >= 2)      { VMW(8); }
    else if (ahead == 1) { VMW(4); }
    else                 { VMW(0); }
    __builtin_amdgcn_sched_barrier(0);
    __builtin_amdgcn_s_barrier();

    const unsigned short* As = AB + cur * 8192;
    const unsigned short* Bs = As + 4096;
    u16x8 af[4], bfv[4];
    #pragma unroll
    for (int mi = 0; mi < 4; mi++)
      af[mi] = *(const u16x8*)&As[(wr * 64 + mi * 16 + lr) * 32 + lkh];
    #pragma unroll
    for (int ni = 0; ni < 4; ni++)
      bfv[ni] = *(const u16x8*)&Bs[(wc * 64 + ni * 16 + lr) * 32 + lkh];
    #pragma unroll
    for (int mi = 0; mi < 4; mi++)
      #pragma unroll
      for (int ni = 0; ni < 4; ni++)
        acc[mi][ni] = __builtin_amdgcn_mfma_f32_16x16x32_bf16(
            __builtin_bit_cast(bf16x8, af[mi]),
            __builtin_bit_cast(bf16x8, bfv[ni]), acc[mi][ni], 0, 0, 0);

    __builtin_amdgcn_s_barrier();
    if (kt + 3 < NT) STAGE(kt + 3, cur);
    cur = (cur == 2) ? 0 : cur + 1;
  }

  const int lcol = l & 15, lrow = (l >> 4) << 2;
  if (EPI == 1) {
    #pragma unroll
    for (int mi = 0; mi < 4; mi++) {
      int rr = row0 + wr * 64 + mi * 16 + lrow;
      #pragma unroll
      for (int ni = 0; ni < 4; ni++) {
        int cc = col0 + wc * 64 + ni * 16 + lcol;
        #pragma unroll
        for (int r = 0; r < 4; r++)
          Cf[(size_t)(rr + r) * 4096 + cc] = acc[mi][ni][r];
      }
    }
  } else if (EPI == 2) {
    const float* Xf = (const float*)Xv;
    const unsigned short* Xh = (const unsigned short*)Xv;
    float part = 0.f;
    #pragma unroll
    for (int mi = 0; mi < 4; mi++) {
      int rr = row0 + wr * 64 + mi * 16 + lrow;
      #pragma unroll
      for (int ni = 0; ni < 4; ni++) {
        int cc = col0 + wc * 64 + ni * 16 + lcol;
        if (cc < Nc) {
          float cd = coldiv ? coldiv[cc] : 1.f;
          #pragma unroll
          for (int r = 0; r < 4; r++) {
            float v = acc[mi][ni][r];
            if (rowdiv) v /= rowdiv[rr + r];
            v /= cd;
            size_t xi = (size_t)(rr + r) * ldX + cc;
            float xval = XBF ? bf2f(Xh[xi]) : Xf[xi];
            float d = xval - v;
            part = fmaf(d, d, part);
          }
        }
      }
    }
    part = blk_red<false>(part);
    if (t == 0) {
      float wgt = (sym && col0 > row0) ? 2.f : 1.f;
      atomicAdd(slot, part * wgt);
    }
  } else { // EPI 3
    const unsigned short* Ph = (const unsigned short*)Xv;
    float a = 0.f, sp = 0.f;
    #pragma unroll
    for (int mi = 0; mi < 4; mi++) {
      int rr = row0 + wr * 64 + mi * 16 + lrow;
      #pragma unroll
      for (int ni = 0; ni < 4; ni++) {
        int cc = col0 + wc * 64 + ni * 16 + lcol;
        #pragma unroll
        for (int r = 0; r < 4; r++) {
          float g = acc[mi][ni][r];
          float p = bf2f(Ph[(size_t)(rr + r) * ldX + cc]);
          float d2 = rowdiv[rr + r] + coldiv[cc] - 2.f * g;
          a = fmaf(p, sqrtf(fmaxf(d2, 1e-12f)), a);
          sp = fmaf(p, logf(p + 1e-10f), sp);
        }
      }
    }
    a = blk_red<false>(a);
    sp = blk_red<false>(sp);
    if (t == 0) { atomicAdd(&slot[ALN], a); atomicAdd(&slot[SPS], sp); }
  }
}

// ============ narrow split-K bf16 MFMA: C[4096][Nc<=128] += A @ Bt^T ============
__global__ __launch_bounds__(256)
void ns_mfma_k(const unsigned short* __restrict__ A, const unsigned short* __restrict__ Bt,
               float* __restrict__ C, int Nc, int K, int KC, int ldC)
{
  __shared__ unsigned short AB[2 * 8192];
  int ks = blockIdx.x & 15, strip = blockIdx.x >> 4;
  const int row0 = strip * 128;
  const int kbase = ks * KC;

  const int t = threadIdx.x, l = t & 63, wv = t >> 6;
  const int wr = wv >> 1, wc = wv & 1;
  const int lr = l & 15, lkh = (l >> 4) << 3;

  f32x4 acc[4][4];
  #pragma unroll
  for (int i = 0; i < 4; i++)
    #pragma unroll
    for (int j = 0; j < 4; j++) acc[i][j] = (f32x4){0.f, 0.f, 0.f, 0.f};

  const int srow = l >> 2;
  const int sk   = (l & 3) << 3;
  const unsigned short* Ab = A  + (size_t)(row0 + srow) * K + kbase + sk;
  const unsigned short* Bb = Bt + (size_t)srow * K + kbase + sk;

  const int NT = KC >> 5;

  auto STAGE = [&](int kt, int buf) {
    unsigned short* As = AB + buf * 8192;
    unsigned short* Bs = As + 4096;
    int k0 = kt << 5;
    #pragma unroll
    for (int h2 = 0; h2 < 2; h2++) {
      int c = wv * 2 + h2;
      gload16(Ab + (size_t)c * 16 * K + k0, As + c * 512);
      gload16(Bb + (size_t)c * 16 * K + k0, Bs + c * 512);
    }
  };

  STAGE(0, 0);
  if (NT > 1) STAGE(1, 1);
  int cur = 0;

  for (int kt = 0; kt < NT; ++kt) {
    if (kt + 1 < NT) { VMW(4); }
    else             { VMW(0); }
    __builtin_amdgcn_sched_barrier(0);
    __builtin_amdgcn_s_barrier();

    const unsigned short* As = AB + cur * 8192;
    const unsigned short* Bs = As + 4096;
    u16x8 af[4], bfv[4];
    #pragma unroll
    for (int mi = 0; mi < 4; mi++)
      af[mi] = *(const u16x8*)&As[(wr * 64 + mi * 16 + lr) * 32 + lkh];
    #pragma unroll
    for (int ni = 0; ni < 4; ni++)
      bfv[ni] = *(const u16x8*)&Bs[(wc * 64 + ni * 16 + lr) * 32 + lkh];
    #pragma unroll
    for (int mi = 0; mi < 4; mi++)
      #pragma unroll
      for (int ni = 0; ni < 4; ni++)
        acc[mi][ni] = __builtin_amdgcn_mfma_f32_16x16x32_bf16(
            __builtin_bit_cast(bf16x8, af[mi]),
            __builtin_bit_cast(bf16x8, bfv[ni]), acc[mi][ni], 0, 0, 0);

    __builtin_amdgcn_s_barrier();
    if (kt + 2 < NT) STAGE(kt + 2, cur);
    cur ^= 1;
  }

  const int lcol = l & 15, lrow = (l >> 4) << 2;
  #pragma unroll
  for (int mi = 0; mi < 4; mi++) {
    int rr = row0 + wr * 64 + mi * 16 + lrow;
    #pragma unroll
    for (int ni = 0; ni < 4; ni++) {
      int cc = wc * 64 + ni * 16 + lcol;
      if (cc < Nc) {
        #pragma unroll
        for (int r = 0; r < 4; r++)
          atomicAdd(&C[(size_t)(rr + r) * ldC + cc], acc[mi][ni][r]);
      }
    }
  }
}

// ---------------- conversion / transpose pre-passes ----------------
__global__ void cvt_k(const float* __restrict__ s, unsigned short* __restrict__ d,
                      int n8, float scale)
{
  int i = blockIdx.x * 256 + threadIdx.x;
  if (i < n8) {
    float4 a = ((const float4*)s)[2 * i], b = ((const float4*)s)[2 * i + 1];
    u16x8 w;
    w[0] = f2bf(a.x * scale); w[1] = f2bf(a.y * scale);
    w[2] = f2bf(a.z * scale); w[3] = f2bf(a.w * scale);
    w[4] = f2bf(b.x * scale); w[5] = f2bf(b.y * scale);
    w[6] = f2bf(b.z * scale); w[7] = f2bf(b.w * scale);
    ((u16x8*)d)[i] = w;
  }
}

// msk [4096][4096] fp32 -> bf16 + fused row sums (mrs pre-zeroed). grid 8192
__global__ void cvt_rs_k(const float* __restrict__ s, unsigned short* __restrict__ d,
                         float* __restrict__ mrs)
{
  int i = blockIdx.x * 256 + threadIdx.x;    // chunk of 8 elems, 512 chunks/row
  float4 a = ((const float4*)s)[2 * i], b = ((const float4*)s)[2 * i + 1];
  u16x8 w;
  w[0] = f2bf(a.x); w[1] = f2bf(a.y); w[2] = f2bf(a.z); w[3] = f2bf(a.w);
  w[4] = f2bf(b.x); w[5] = f2bf(b.y); w[6] = f2bf(b.z); w[7] = f2bf(b.w);
  ((u16x8*)d)[i] = w;
  float s8 = a.x + a.y + a.z + a.w + b.x + b.y + b.z + b.w;
  float ws = wave_red_sum(s8);
  if ((threadIdx.x & 63) == 0) atomicAdd(&mrs[i >> 9], ws);
}

// [4096][3000] fp32 -> [4096][3072] bf16 zero-padded
__global__ void cvt_pad_k(const float* __restrict__ s, unsigned short* __restrict__ d)
{
  int i = blockIdx.x * 256 + threadIdx.x;
  int row = i / 384, c8 = (i - row * 384) * 8;
  u16x8 w = (u16x8)0;
  if (c8 < kIN) {
    const float* sp = s + (size_t)row * kIN + c8;
    float4 a = *(const float4*)sp, b = *(const float4*)(sp + 4);
    w[0] = f2bf(a.x); w[1] = f2bf(a.y); w[2] = f2bf(a.z); w[3] = f2bf(a.w);
    w[4] = f2bf(b.x); w[5] = f2bf(b.y); w[6] = f2bf(b.z); w[7] = f2bf(b.w);
  }
  ((u16x8*)d)[i] = w;
}

// [4096][128] fp32 cols 0..63 -> [4096][64] bf16
__global__ void cvt_cols_k(const float* __restrict__ s, unsigned short* __restrict__ d)
{
  int i = blockIdx.x * 256 + threadIdx.x;
  int row = i >> 3, c8 = (i & 7) * 8;
  const float* sp = s + (size_t)row * 128 + c8;
  float4 a = *(const float4*)sp, b = *(const float4*)(sp + 4);
  u16x8 w;
  w[0] = f2bf(a.x); w[1] = f2bf(a.y); w[2] = f2bf(a.z); w[3] = f2bf(a.w);
  w[4] = f2bf(b.x); w[5] = f2bf(b.y); w[6] = f2bf(b.z); w[7] = f2bf(b.w);
  ((u16x8*)d)[i] = w;
}

// transpose+convert: src fp32 [R][C] (ld sld) -> dst bf16 (ld dld), optional relu
template<bool RELU>
__global__ void tr_k(const float* __restrict__ src, unsigned short* __restrict__ dst,
                     int R, int C, int sld, int dld)
{
  __shared__ float tile[32][33];
  int c0 = blockIdx.x * 32, r0 = blockIdx.y * 32;
  int tr_ = threadIdx.x >> 3, tc4 = (threadIdx.x & 7) << 2;
  #pragma unroll
  for (int j = 0; j < 4; j++) {
    int r = r0 + tr_, c = c0 + tc4 + j;
    float v = (r < R && c < C) ? src[(size_t)r * sld + c] : 0.f;
    if (RELU) v = fmaxf(v, 0.f);
    tile[tr_][tc4 + j] = v;
  }
  __syncthreads();
  u16x4 wv;
  #pragma unroll
  for (int j = 0; j < 4; j++) wv[j] = f2bf(tile[tc4 + j][tr_]);
  *(u16x4*)&dst[(size_t)(c0 + tr_) * dld + r0 + tc4] = wv;
}

// ---------------- small fp32 GEMM (64-col weight GEMMs only) ----------------
__global__ __launch_bounds__(256)
void gemm_small_k(const float* __restrict__ A, const float* __restrict__ B,
                  float* __restrict__ C, int M, int Nc, int K,
                  int ldA, int ldB, int ldC)
{
  __shared__ float As[16][68];
  __shared__ float Bs[16][68];
  int tid = threadIdx.x;
  int tx = tid & 15, ty = tid >> 4;
  int row0 = blockIdx.y * 64, col0 = blockIdx.x * 64;
  float acc[4][4] = {};

  for (int k0 = 0; k0 < K; k0 += 16) {
    {
      int m = tid >> 2, kk = (tid & 3) << 2;
      const float* ap = A + (size_t)(row0 + m) * ldA + k0 + kk;
      float4 v = *(const float4*)ap;
      As[kk + 0][m] = v.x; As[kk + 1][m] = v.y; As[kk + 2][m] = v.z; As[kk + 3][m] = v.w;
    }
    {
      int kk = tid >> 4, c = (tid & 15) << 2;
      const float* bp = B + (size_t)(k0 + kk) * ldB + col0 + c;
      #pragma unroll
      for (int i = 0; i < 4; i++)
        Bs[kk][c + i] = (col0 + c + i < Nc) ? bp[i] : 0.f;
    }
    __syncthreads();
    #pragma unroll
    for (int kk = 0; kk < 16; kk++) {
      float4 a4 = *(const float4*)&As[kk][ty << 2];
      float4 b4 = *(const float4*)&Bs[kk][tx << 2];
      float av[4] = {a4.x, a4.y, a4.z, a4.w};
      float bv[4] = {b4.x, b4.y, b4.z, b4.w};
      #pragma unroll
      for (int i = 0; i < 4; i++)
        #pragma unroll
        for (int j = 0; j < 4; j++)
          acc[i][j] = fmaf(av[i], bv[j], acc[i][j]);
    }
    __syncthreads();
  }
  #pragma unroll
  for (int i = 0; i < 4; i++) {
    int r = row0 + (ty << 2) + i;
    #pragma unroll
    for (int j = 0; j < 4; j++) {
      int c = col0 + (tx << 2) + j;
      if (c < Nc) C[(size_t)r * ldC + c] = acc[i][j];
    }
  }
}

// ---------------- fused Sinkhorn passes ----------------
__global__ __launch_bounds__(256)
void sink_k(float* __restrict__ P, unsigned short* __restrict__ Pb,
            const float* __restrict__ cs_in, float* __restrict__ cs_out,
            float* __restrict__ rs, int mode)
{
  int tid = threadIdx.x;
  int r0 = blockIdx.x * 8;
  float csl[16] = {};
  float cdiv[16];
  if (mode != 0) {
    #pragma unroll
    for (int t = 0; t < 4; t++) {
      float4 c4 = ((const float4*)cs_in)[tid + t * 256];
      cdiv[4 * t + 0] = 1.f / (4096.f * c4.x);
      cdiv[4 * t + 1] = 1.f / (4096.f * c4.y);
      cdiv[4 * t + 2] = 1.f / (4096.f * c4.z);
      cdiv[4 * t + 3] = 1.f / (4096.f * c4.w);
    }
  }
  for (int rr = 0; rr < 8; rr++) {
    int row = r0 + rr;
    float4* prow = (float4*)(P + (size_t)row * 4096);
    float4 r[4];
    #pragma unroll
    for (int t = 0; t < 4; t++) r[t] = prow[tid + t * 256];

    if (mode == 0) {
      float m = -3.4e38f;
      #pragma unroll
      for (int t = 0; t < 4; t++)
        m = fmaxf(m, fmaxf(fmaxf(r[t].x, r[t].y), fmaxf(r[t].z, r[t].w)));
      m = blk_red<true>(m);
      float s = 0.f;
      #pragma unroll
      for (int t = 0; t < 4; t++) {
        r[t].x = expf(r[t].x - m); r[t].y = expf(r[t].y - m);
        r[t].z = expf(r[t].z - m); r[t].w = expf(r[t].w - m);
        s += r[t].x + r[t].y + r[t].z + r[t].w;
      }
      s = blk_red<false>(s);
      float f = 1.f / (s * 4096.f);
      #pragma unroll
      for (int t = 0; t < 4; t++) {
        r[t].x *= f; r[t].y *= f; r[t].z *= f; r[t].w *= f;
        prow[tid + t * 256] = r[t];
        csl[4 * t + 0] += r[t].x; csl[4 * t + 1] += r[t].y;
        csl[4 * t + 2] += r[t].z; csl[4 * t + 3] += r[t].w;
      }
    } else {
      float s = 0.f;
      #pragma unroll
      for (int t = 0; t < 4; t++) {
        r[t].x *= cdiv[4 * t + 0]; r[t].y *= cdiv[4 * t + 1];
        r[t].z *= cdiv[4 * t + 2]; r[t].w *= cdiv[4 * t + 3];
        s += r[t].x + r[t].y + r[t].z + r[t].w;
      }
      s = blk_red<false>(s);
      if (mode == 1) {
        float f = 1.f / (4096.f * s);
        #pragma unroll
        for (int t = 0; t < 4; t++) {
          r[t].x *= f; r[t].y *= f; r[t].z *= f; r[t].w *= f;
          prow[tid + t * 256] = r[t];
          csl[4 * t + 0] += r[t].x; csl[4 * t + 1] += r[t].y;
          csl[4 * t + 2] += r[t].z; csl[4 * t + 3] += r[t].w;
        }
      } else {
        if (tid == 0) rs[row] = s;
        #pragma unroll
        for (int t = 0; t < 4; t++) {
          prow[tid + t * 256] = r[t];
          u16x4 w;
          w[0] = f2bf(r[t].x); w[1] = f2bf(r[t].y);
          w[2] = f2bf(r[t].z); w[3] = f2bf(r[t].w);
          *(u16x4*)&Pb[(size_t)row * 4096 + 4 * (tid + t * 256)] = w;
          csl[4 * t + 0] += r[t].x; csl[4 * t + 1] += r[t].y;
          csl[4 * t + 2] += r[t].z; csl[4 * t + 3] += r[t].w;
        }
      }
    }
  }
  #pragma unroll
  for (int t = 0; t < 4; t++) {
    int j = 4 * (tid + t * 256);
    atomicAdd(&cs_out[j + 0], csl[4 * t + 0]);
    atomicAdd(&cs_out[j + 1], csl[4 * t + 1]);
    atomicAdd(&cs_out[j + 2], csl[4 * t + 2]);
    atomicAdd(&cs_out[j + 3], csl[4 * t + 3]);
  }
}

__global__ void relu_k(const float* __restrict__ in, float* __restrict__ out, int n)
{
  int i = blockIdx.x * blockDim.x + threadIdx.x;
  if (i < n) out[i] = fmaxf(in[i], 0.f);
}

__global__ void gather_k(float* __restrict__ XP, const int* __restrict__ perm)
{
  int gid = blockIdx.x * 256 + threadIdx.x;
  int i = gid >> 6, j = gid & 63;
  XP[(size_t)i * 128 + 64 + j] = XP[(size_t)perm[i] * 128 + j];
}

__global__ void sqnorm_k(const float* __restrict__ H, int ld, float* __restrict__ outv)
{
  int gid = blockIdx.x * 256 + threadIdx.x;
  int row = gid >> 6, j = gid & 63;
  float v = H[(size_t)row * ld + j];
  float p = wave_red_sum(v * v);
  if (j == 0) outv[row] = p;
}

__global__ void readout_k(const float* __restrict__ vs2, const float* __restrict__ mrs,
                          float* __restrict__ g2)
{
  int q = blockIdx.x, j = threadIdx.x;
  float v = vs2[(size_t)q * 64 + j] / mrs[q >> 1];
  float p = v * v;
  #pragma unroll
  for (int s = 1; s < 64; s <<= 1) p += __shfl_xor(p, s, 64);
  float nrm = sqrtf(p);
  v = v / fmaxf(nrm, 1e-12f);
  g2[(size_t)q * 64 + j] = 1.f / (1.f + expf(-v));
}

__device__ __forceinline__ float bce_term(float x, float y) {
  return fmaxf(x, 0.f) - x * y + log1pf(expf(-fabsf(x)));
}

__global__ void disc_k(const float* __restrict__ G2, const float* __restrict__ W2,
                       const float* __restrict__ lab, const float* __restrict__ bptr,
                       float* __restrict__ acc)
{
  int i = blockIdx.x, j = threadIdx.x;
  float gj  = G2[(size_t)(2 * i) * 64 + j];
  float gaj = G2[(size_t)(2 * i + 1) * 64 + j];
  float hw  = W2[(size_t)(2 * i) * 64 + j];
  float haw = W2[(size_t)(2 * i + 1) * 64 + j];
  float s1 = hw * gj, s2 = haw * gj, s1a = haw * gaj, s2a = hw * gaj;
  #pragma unroll
  for (int s = 1; s < 64; s <<= 1) {
    s1  += __shfl_xor(s1, s, 64);
    s2  += __shfl_xor(s2, s, 64);
    s1a += __shfl_xor(s1a, s, 64);
    s2a += __shfl_xor(s2a, s, 64);
  }
  if (j == 0) {
    float b = bptr[0];
    float y0 = lab[i * 2 + 0], y1 = lab[i * 2 + 1];
    float t = bce_term(s1 + b, y0) + bce_term(s2 + b, y1)
            + bce_term(s1a + b, y0) + bce_term(s2a + b, y1);
    atomicAdd(&acc[SL], t);
  }
}

__global__ __launch_bounds__(256)
void finalize_k(const float* __restrict__ acc, const float* __restrict__ cs,
                float* __restrict__ out)
{
  int tid = threadIdx.x;
  float invm2 = 1.f / (float)kN;
  float t = 0.f;
  for (int j = tid; j < kN; j += 256) {
    float q = cs[j];
    t += q * (logf(q) - invm2);
  }
  t = blk_red<false>(t);
  if (tid == 0) {
    float kld_pq = t * invm2;
    float kld_pp = invm2 * (logf(invm2) - invm2);
    out[0] = acc[SL] / (2.f * (float)kN);
    out[1] = acc[FEAT] / ((float)kN * (float)kIN);
    out[2] = acc[ALN];
    out[3] = (acc[FXA] + acc[FXB]) / ((float)kN * (float)kIN);
    out[4] = sqrtf(acc[SM1]) / (float)kN + sqrtf(acc[SM2]) / (float)kN;
    out[5] = (kld_pq - kld_pp) * (float)kN;
    out[6] = -acc[SPS];
  }
}

extern "C" void kernel_launch(void* const* d_in, const int* in_sizes, int n_in,
                              void* d_out, int out_size, void* d_ws, size_t ws_size,
                              hipStream_t stream)
{
  (void)in_sizes; (void)n_in; (void)out_size; (void)ws_size;
  const float* feat  = (const float*)d_in[0];
  const float* adjs  = (const float*)d_in[1];
  const float* gmask = (const float*)d_in[2];
  const float* labs  = (const float*)d_in[3];
  const float* dists = (const float*)d_in[4];
  const int*   perms = (const int*)d_in[5];
  const float* encW  = (const float*)d_in[6];
  const float* decW  = (const float*)d_in[7];
  const float* MsW   = (const float*)d_in[8];
  const float* discW = (const float*)d_in[9];
  const float* discb = (const float*)d_in[10];
  float* out = (float*)d_out;

  const size_t SZNN = (size_t)kN * kN;

  char* cur = (char*)d_ws;
  auto alloc = [&](size_t bytes) {
    char* p = cur;
    cur += (bytes + 255) & ~(size_t)255;
    return p;
  };
  float* P            = (float*)alloc(SZNN * 4);          // fp32 P; later reused for Tb
  unsigned short* Pb  = (unsigned short*)alloc(SZNN * 2);
  unsigned short* PbT = (unsigned short*)alloc(SZNN * 2);
  unsigned short* Db  = (unsigned short*)alloc(SZNN * 2);
  unsigned short* ajb = (unsigned short*)alloc(SZNN * 2); // adj/msk bf16; later ftb
  unsigned short* xb  = (unsigned short*)alloc((size_t)kN * kINp * 2);
  unsigned short* dWtb= (unsigned short*)alloc((size_t)kINp * kLAT * 2);
  unsigned short* ahb = (unsigned short*)alloc((size_t)kN * kLAT * 2);
  unsigned short* encWtp = (unsigned short*)alloc((size_t)128 * kINp * 2);
  unsigned short* XPt = (unsigned short*)alloc((size_t)128 * kN * 2);
  unsigned short* hbTp= (unsigned short*)alloc((size_t)128 * kN * 2);
  unsigned short* HRt = (unsigned short*)alloc((size_t)128 * kN * 2);
  unsigned short* smb = (unsigned short*)alloc((size_t)kN * kLAT * 2);
  unsigned short* tmb = (unsigned short*)alloc((size_t)kN * kLAT * 2);
  unsigned short* h0b = (unsigned short*)alloc((size_t)kN * kLAT * 2);
  unsigned short* h1b = (unsigned short*)alloc((size_t)kN * kLAT * 2);
  float* XP  = (float*)alloc((size_t)kN * 128 * 4);
  float* HH0 = (float*)alloc((size_t)kN * 128 * 4);
  float* HH1 = (float*)alloc((size_t)kN * 128 * 4);
  float* HR  = (float*)alloc((size_t)kN * 128 * 4);
  float* VS  = (float*)alloc((size_t)kN * 128 * 4);
  float* G2  = (float*)alloc((size_t)kN * 128 * 4);
  float* W2  = (float*)alloc((size_t)kN * 128 * 4);
  float* SM_ = (float*)alloc((size_t)kN * kLAT * 4);
  float* TM_ = (float*)alloc((size_t)kN * kLAT * 4);
  float* ah  = (float*)alloc((size_t)kN * kLAT * 4);
  float* sns = (float*)alloc(kN * 4);
  float* snt = (float*)alloc(kN * 4);
  float* rs  = (float*)alloc(kN * 4);
  float* cs  = (float*)alloc(kN * 4);
  float* csA = (float*)alloc(kN * 4);
  float* csB = (float*)alloc(kN * 4);
  float* mrs = (float*)alloc(kN * 4);
  float* acc = (float*)alloc(NSLOT * 4);

  unsigned short* Tb  = (unsigned short*)P;     // alias: fp32 P dead before Tb written
  unsigned short* ftb = ajb;                    // alias: adj/msk bf16 dead after slices

  hipMemsetAsync(acc, 0, NSLOT * sizeof(float), stream);

  // ---------------- per-slice losses ----------------
  for (int k = 0; k < 2; k++) {
    const float* x    = feat  + (size_t)k * kN * kIN;
    const float* adj  = adjs  + (size_t)k * SZNN;
    const float* msk  = gmask + (size_t)k * SZNN;
    const float* lab  = labs  + (size_t)k * kN * 2;
    const int*   perm = perms + (size_t)k * kN;
    const float* eW   = encW  + (size_t)k * kIN * kLAT;
    const float* dW   = decW  + (size_t)k * kLAT * kIN;
    float* HHk = (k == 0) ? HH0 : HH1;

    cvt_pad_k<<<6144, 256, 0, stream>>>(x, xb);
    hipMemsetAsync(encWtp, 0, (size_t)128 * kINp * 2, stream);
    tr_k<false><<<dim3(2, (kIN + 31) / 32), 256, 0, stream>>>(eW, encWtp, kIN, kLAT, kLAT, kINp);
    hipMemsetAsync(XP, 0, (size_t)kN * 128 * 4, stream);
    ns_mfma_k<<<512, 256, 0, stream>>>(xb, encWtp, XP, kLAT, kINp, kINp / 16, 128);
    gather_k<<<kN * 64 / 256, 256, 0, stream>>>(XP, perm);
    tr_k<false><<<dim3(4, 128), 256, 0, stream>>>(XP, XPt, kN, 128, 128, kN);
    cvt_k<<<(int)(SZNN / 8 / 256), 256, 0, stream>>>(adj, ajb, (int)(SZNN / 8), 1.f);
    hipMemsetAsync(HHk, 0, (size_t)kN * 128 * 4, stream);
    ns_mfma_k<<<512, 256, 0, stream>>>(ajb, XPt, HHk, 128, kN, kN / 16, 128);
    hipMemsetAsync(hbTp, 0, (size_t)128 * kN * 2, stream);
    tr_k<false><<<dim3(2, 128), 256, 0, stream>>>(HHk, hbTp, kN, kLAT, 128, kN);
    hipMemsetAsync(ah, 0, (size_t)kN * kLAT * 4, stream);
    ns_mfma_k<<<512, 256, 0, stream>>>(ajb, hbTp, ah, kLAT, kN, kN / 16, kLAT);
    cvt_k<<<128, 256, 0, stream>>>(ah, ahb, kN * kLAT / 8, 1.f);
    tr_k<false><<<dim3(kINp / 32, 2), 256, 0, stream>>>(dW, dWtb, kLAT, kIN, kIN, kLAT);
    bt_mfma_k<2, 1><<<(kINp / 128) * 32, 256, 0, stream>>>(
        ahb, dWtb, nullptr, nullptr, xb, nullptr, nullptr, &acc[FEAT],
        kINp / 128, kIN, kLAT, kINp, 0);
    relu_k<<<kN * 128 / 256, 256, 0, stream>>>(HHk, HR, kN * 128);
    tr_k<true><<<dim3(4, 128), 256, 0, stream>>>(HHk, HRt, kN, 128, 128, kN);
    // msk -> bf16 with fused row sums
    hipMemsetAsync(mrs, 0, kN * 4, stream);
    cvt_rs_k<<<(int)(SZNN / 8 / 256), 256, 0, stream>>>(msk, ajb, mrs);
    hipMemsetAsync(VS, 0, (size_t)kN * 128 * 4, stream);
    ns_mfma_k<<<512, 256, 0, stream>>>(ajb, HRt, VS, 128, kN, kN / 16, 128);
    readout_k<<<2 * kN, 64, 0, stream>>>(VS, mrs, G2);
    gemm_small_k<<<dim3(1, 128), 256, 0, stream>>>(HR, discW, W2, 2 * kN, kLAT, kLAT,
                                                   kLAT, kLAT, kLAT);
    disc_k<<<kN, 64, 0, stream>>>(G2, W2, lab, discb, acc);
  }

  // ---------------- alignment losses ----------------
  const float* f0 = feat;
  const float* f1 = feat + (size_t)kN * kIN;
  const float* D0 = dists;
  const float* D1 = dists + SZNN;

  gemm_small_k<<<dim3(1, 64), 256, 0, stream>>>(HH0, MsW, SM_, kN, kLAT, kLAT, 128, kLAT, kLAT);
  gemm_small_k<<<dim3(1, 64), 256, 0, stream>>>(HH1, MsW, TM_, kN, kLAT, kLAT, 128, kLAT, kLAT);
  cvt_k<<<128, 256, 0, stream>>>(SM_, smb, kN * kLAT / 8, 0.125f);
  cvt_k<<<128, 256, 0, stream>>>(TM_, tmb, kN * kLAT / 8, 1.f);
  // P = srcM @ tgtM^T / 8  (128-tile MFMA, fp32 store)
  bt_mfma_k<1, 0><<<1024, 256, 0, stream>>>(smb, tmb, nullptr, P, nullptr, nullptr, nullptr,
                                            nullptr, 32, kN, kLAT, 0, 0);

  // fused sinkhorn: softmax + 3 iters + final marginals + bf16 P, 4 passes
  hipMemsetAsync(csA, 0, kN * 4, stream);
  sink_k<<<512, 256, 0, stream>>>(P, nullptr, nullptr, csA, nullptr, 0);
  hipMemsetAsync(csB, 0, kN * 4, stream);
  sink_k<<<512, 256, 0, stream>>>(P, nullptr, csA, csB, nullptr, 1);
  hipMemsetAsync(csA, 0, kN * 4, stream);
  sink_k<<<512, 256, 0, stream>>>(P, nullptr, csB, csA, nullptr, 1);
  hipMemsetAsync(cs, 0, kN * 4, stream);
  sink_k<<<512, 256, 0, stream>>>(P, Pb, csA, cs, rs, 2);

  // PbT = bf16(P^T) — last read of fp32 P
  tr_k<false><<<dim3(kN / 32, kN / 32), 256, 0, stream>>>(P, PbT, kN, kN, kN, kN);

  // align + sparsity: h0@h1^T (128-tile MFMA, EPI3)
  cvt_cols_k<<<128, 256, 0, stream>>>(HH0, h0b);
  cvt_cols_k<<<128, 256, 0, stream>>>(HH1, h1b);
  sqnorm_k<<<kN * 64 / 256, 256, 0, stream>>>(HH0, 128, sns);
  sqnorm_k<<<kN * 64 / 256, 256, 0, stream>>>(HH1, 128, snt);
  bt_mfma_k<3, 1><<<1024, 256, 0, stream>>>(h0b, h1b, nullptr, nullptr, Pb, sns, snt, acc,
                                            32, kN, kLAT, kN, 0);

  // loss_align_fix (128-tile bt, 768 blocks — full grid fill)
  tr_k<false><<<dim3(kINp / 32, kN / 32), 256, 0, stream>>>(f1, ftb, kN, kIN, kIN, kN);
  bt_mfma_k<2, 0><<<(kINp / 128) * 32, 256, 0, stream>>>(
      Pb, ftb, nullptr, nullptr, f0, rs, nullptr, &acc[FXA], kINp / 128, kIN, kN, kIN, 0);
  tr_k<false><<<dim3(kINp / 32, kN / 32), 256, 0, stream>>>(f0, ftb, kN, kIN, kIN, kN);
  bt_mfma_k<2, 0><<<(kINp / 128) * 32, 256, 0, stream>>>(
      PbT, ftb, nullptr, nullptr, f1, cs, nullptr, &acc[FXB], kINp / 128, kIN, kN, kIN, 0);

  // loss_maintain 1: Tb = (P@D1)/rs (g8 dense) ; SM1 = sum((D0 - (Tb@P^T)/rs)^2) sym (bt)
  cvt_k<<<(int)(SZNN / 8 / 256), 256, 0, stream>>>(D1, Db, (int)(SZNN / 8), 1.f);
  g8_mfma_k<<<256, 512, 0, stream>>>(Pb, Db, Tb, rs, kN);
  bt_mfma_k<2, 0><<<528, 256, 0, stream>>>(Tb, Pb, nullptr, nullptr, D0, nullptr, rs,
                                           &acc[SM1], 32, kN, kN, kN, 1);
  // loss_maintain 2: Tb = (P^T@D0)/cs (g8 dense) ; SM2 = sum((D1 - (Tb@P)/cs)^2) sym (bt)
  cvt_k<<<(int)(SZNN / 8 / 256), 256, 0, stream>>>(D0, Db, (int)(SZNN / 8), 1.f);
  g8_mfma_k<<<256, 512, 0, stream>>>(PbT, Db, Tb, cs, kN);
  bt_mfma_k<2, 0><<<528, 256, 0, stream>>>(Tb, PbT, nullptr, nullptr, D1, nullptr, cs,
                                           &acc[SM2], 32, kN, kN, kN, 1);

  finalize_k<<<1, 256, 0, stream>>>(acc, cs, out);
}

// Round 8
// 2051.148 us; speedup vs baseline: 1.0249x; 1.0048x over previous
//
#include <hip/hip_runtime.h>
#include <cmath>

// Problem constants
constexpr int kN   = 4096;
constexpr int kIN  = 3000;
constexpr int kINp = 3072;   // kIN padded to 128-multiple
constexpr int kLAT = 64;

enum { SL = 0, FEAT, ALN, FXA, FXB, SM1, SM2, SPS, NSLOT };

typedef __bf16 bf16x8 __attribute__((ext_vector_type(8)));
typedef float f32x4 __attribute__((ext_vector_type(4)));
typedef unsigned short u16x8 __attribute__((ext_vector_type(8)));
typedef unsigned short u16x4 __attribute__((ext_vector_type(4)));

// ---------------- reduction helpers ----------------
template<bool IS_MAX>
__device__ __forceinline__ float blk_red(float v) {
  __shared__ float buf[8];
  #pragma unroll
  for (int s = 32; s > 0; s >>= 1) {
    float o = __shfl_down(v, s, 64);
    v = IS_MAX ? fmaxf(v, o) : (v + o);
  }
  int lane = threadIdx.x & 63, wv = threadIdx.x >> 6, nw = blockDim.x >> 6;
  __syncthreads();
  if (lane == 0) buf[wv] = v;
  __syncthreads();
  float r = buf[0];
  for (int i = 1; i < nw; i++) r = IS_MAX ? fmaxf(r, buf[i]) : (r + buf[i]);
  return r;
}

__device__ __forceinline__ float wave_red_sum(float v) {
  #pragma unroll
  for (int s = 32; s > 0; s >>= 1) v += __shfl_down(v, s, 64);
  return v;
}

// fp32 -> bf16 RNE ; bf16 -> fp32
__device__ __forceinline__ unsigned short f2bf(float f) {
  unsigned u = __builtin_bit_cast(unsigned, f);
  u += 0x7fffu + ((u >> 16) & 1u);
  return (unsigned short)(u >> 16);
}
__device__ __forceinline__ float bf2f(unsigned short h) {
  return __builtin_bit_cast(float, (unsigned)h << 16);
}

// async global->LDS, 16B per lane
__device__ __forceinline__ void gload16(const unsigned short* g, unsigned short* l) {
  __builtin_amdgcn_global_load_lds(
      (const __attribute__((address_space(1))) unsigned int*)g,
      (__attribute__((address_space(3))) unsigned int*)l, 16, 0, 0);
}

#define VMW(n) asm volatile("s_waitcnt vmcnt(" #n ")" ::: "memory")

// ============================================================================
// 256x256-tile 8-phase bf16 MFMA GEMM: Cb = bf16((A @ Bt^T)/rowdiv). K mult 128.
// Dense only, grid = 256 (16x16 tiles), 512 thr = 8 waves (2M x 4N).
// m201-faithful phase ordering: {ds_read subtile ; STG prefetch} BEFORE the
// leading barrier (latency hides under barrier wait + co-wave MFMA), then
// barrier -> lgkmcnt(0) -> 16 MFMA -> VMW(next phase's regions) -> barrier.
// Verify ledger: region read at phase p is all-waves-verified at p-1's
// trailing barrier. Steady VMW(8) at even-phase ends; last iter {8,4,0}.
// Epilogue: per-wave LDS transpose -> u16x4 coalesced 128B-line C stores.
// ============================================================================
__global__ __launch_bounds__(512, 2)
void g8_mfma_k(const unsigned short* __restrict__ A, const unsigned short* __restrict__ Bt,
               unsigned short* __restrict__ Cb, const float* __restrict__ rowdiv, int K)
{
  __shared__ unsigned short AB[65536];   // 128 KB

  int orig = blockIdx.x;
  int x = orig & 7, tt = orig >> 3;
  int bx = tt >> 1, by = x * 2 + (tt & 1);   // XCD x owns row-tiles 2x..2x+1
  const int row0 = by * 256, col0 = bx * 256;

  const int t = threadIdx.x, l = t & 63, wv = t >> 6;
  const int wr = wv >> 2, wc = wv & 3;           // 2M x 4N wave grid
  const int lr = l & 15;
  const int sA = (l >> 4) ^ ((lr >> 1) & 3);     // swizzled 16B slot for frag reads

  f32x4 acc[8][4];
  #pragma unroll
  for (int i = 0; i < 8; i++)
    #pragma unroll
    for (int j = 0; j < 4; j++) acc[i][j] = (f32x4){0.f, 0.f, 0.f, 0.f};

  const int NT = K >> 6;        // K-tiles of 64
  const int NI = NT >> 1;       // iterations (2 K-tiles each)

  // per-lane staging source bases (pre-swizzled k-slot; rule #21 both-sides)
  const int srow  = l >> 2;
  const int sslot = (l & 3) ^ ((l >> 3) & 3);
  const unsigned short* Ap = A  + (size_t)(row0 + srow) * K + sslot * 8;
  const unsigned short* Bp = Bt + (size_t)(col0 + srow) * K + sslot * 8;

  // stage one 16KB region r of tile `tile` (r: 0=Ak0 1=Bk0 2=Ak1 3=Bk1)
  auto STG = [&](int tile, int r) {
    if (tile >= NT) return;
    int buf = tile & 1, ks = r >> 1;
    const unsigned short* src = (r & 1) ? Bp : Ap;
    unsigned short* dst = AB + buf * 32768 + r * 8192;
    size_t koff = (size_t)tile * 64 + ks * 32;
    #pragma unroll
    for (int j = 0; j < 2; j++) {
      int c = wv * 2 + j;
      gload16(src + (size_t)c * 16 * K + koff, dst + c * 512);
    }
  };

  u16x8 af[8], bfv[2];

#define MFMA16(AV, BV, ACC) \
  ACC = __builtin_amdgcn_mfma_f32_16x16x32_bf16( \
      __builtin_bit_cast(bf16x8, AV), __builtin_bit_cast(bf16x8, BV), ACC, 0, 0, 0)

// ISA=1: load af[8]+bfv01, MFMA into acc[.][0,1]. ISA=0: load bfv23 only,
// MFMA into acc[.][2,3]. VN: vmcnt verify for NEXT phase (-1 = none).
#define PH(ISA, VN, BUF, KS, STILE, SR)                                        \
  {                                                                            \
    {                                                                          \
      const unsigned short* ab = &AB[(BUF) * 32768 + (KS) * 16384];            \
      const unsigned short* bb = ab + 8192;                                    \
      if (ISA) {                                                               \
        _Pragma("unroll")                                                      \
        for (int mi = 0; mi < 8; mi++)                                         \
          af[mi] = *(const u16x8*)&ab[(wr * 128 + mi * 16 + lr) * 32 + sA * 8];\
        bfv[0] = *(const u16x8*)&bb[(wc * 64 +  0 + lr) * 32 + sA * 8];        \
        bfv[1] = *(const u16x8*)&bb[(wc * 64 + 16 + lr) * 32 + sA * 8];        \
      } else {                                                                 \
        bfv[0] = *(const u16x8*)&bb[(wc * 64 + 32 + lr) * 32 + sA * 8];        \
        bfv[1] = *(const u16x8*)&bb[(wc * 64 + 48 + lr) * 32 + sA * 8];        \
      }                                                                        \
    }                                                                          \
    if ((STILE) >= 0) STG(STILE, SR);                                          \
    __builtin_amdgcn_sched_barrier(0);                                         \
    __builtin_amdgcn_s_barrier();                                              \
    asm volatile("s_waitcnt lgkmcnt(0)" ::: "memory");                         \
    __builtin_amdgcn_sched_barrier(0);                                         \
    __builtin_amdgcn_s_setprio(1);                                             \
    _Pragma("unroll")                                                          \
    for (int mi = 0; mi < 8; mi++) {                                           \
      MFMA16(af[mi], bfv[0], acc[mi][(ISA) ? 0 : 2]);                          \
      MFMA16(af[mi], bfv[1], acc[mi][(ISA) ? 1 : 3]);                          \
    }                                                                          \
    __builtin_amdgcn_s_setprio(0);                                             \
    if ((VN) == 8) VMW(8); else if ((VN) == 4) VMW(4);                         \
    else if ((VN) == 0) VMW(0);                                                \
    __builtin_amdgcn_sched_barrier(0);                                         \
    __builtin_amdgcn_s_barrier();                                              \
  }

  // prologue: 6 regions; verify t0{r0,r1} for phase 1, then all-waves barrier
  STG(0, 0); STG(0, 1); STG(0, 2); STG(0, 3); STG(1, 0); STG(1, 1);
  VMW(8);
  __builtin_amdgcn_sched_barrier(0);
  __builtin_amdgcn_s_barrier();

  for (int i = 0; i < NI - 1; ++i) {
    int T = 2 * i;
    PH(1, -1, 0, 0, T + 1, 2);   // p1: reads b0{r0,r1}
    PH(0,  8, 0, 0, T + 1, 3);   // p2: verify b0{r2,r3} for p3
    PH(1, -1, 0, 1, T + 2, 0);   // p3
    PH(0,  8, 0, 1, T + 2, 1);   // p4: verify b1{r0,r1}
    PH(1, -1, 1, 0, T + 2, 2);   // p5
    PH(0,  8, 1, 0, T + 2, 3);   // p6: verify b1{r2,r3}
    PH(1, -1, 1, 1, T + 3, 0);   // p7
    PH(0,  8, 1, 1, T + 3, 1);   // p8: verify next-iter b0{r0,r1}
  }
  {
    int T = 2 * (NI - 1);
    PH(1, -1, 0, 0, T + 1, 2);
    PH(0,  8, 0, 0, T + 1, 3);
    PH(1, -1, 0, 1, -1, 0);
    PH(0,  4, 0, 1, -1, 0);
    PH(1, -1, 1, 0, -1, 0);
    PH(0,  0, 1, 0, -1, 0);
    PH(1, -1, 1, 1, -1, 0);
    PH(0, -1, 1, 1, -1, 0);
  }
#undef PH
#undef MFMA16

  // ---- epilogue: per-wave LDS transpose -> coalesced 128B-line stores ----
  unsigned short* lw = AB + wv * 8192;         // 16 KB private per wave
  const int lcol = l & 15, lrow4 = l >> 4;
  #pragma unroll
  for (int half = 0; half < 2; ++half) {
    #pragma unroll
    for (int mi2 = 0; mi2 < 4; ++mi2) {
      int mi = half * 4 + mi2;
      #pragma unroll
      for (int nn = 0; nn < 4; ++nn)
        #pragma unroll
        for (int r = 0; r < 4; ++r) {
          float v = acc[mi][nn][r];
          if (rowdiv) v /= rowdiv[row0 + wr * 128 + mi * 16 + lrow4 * 4 + r];
          lw[(mi2 * 16 + lrow4 * 4 + r) * 68 + nn * 16 + lcol] = f2bf(v);
        }
    }
    #pragma unroll
    for (int rr2 = 0; rr2 < 16; ++rr2) {
      int lrr = rr2 * 4 + lrow4;
      u16x4 w4 = *(const u16x4*)&lw[lrr * 68 + lcol * 4];
      int grow = row0 + wr * 128 + half * 64 + lrr;
      int gcol = col0 + wc * 64 + lcol * 4;
      *(u16x4*)&Cb[(size_t)grow * 4096 + gcol] = w4;
    }
  }
}

// ================== 128-tile bf16 MFMA GEMM: C = A @ Bt^T ==================
// 3-deep pipeline, counted vmcnt. Dense strip decode or sym triangular (528).
// EPI 1: Cf = acc (fp32);  EPI 2: slot += wgt*sum (X - acc/rd/cd)^2 (X fp32/bf16)
// EPI 3: align+sparsity epilogue
template<int EPI, int XBF>
__global__ __launch_bounds__(256)
void bt_mfma_k(const unsigned short* __restrict__ A, const unsigned short* __restrict__ Bt,
               unsigned short* __restrict__ Cb, float* __restrict__ Cf,
               const void* __restrict__ Xv,
               const float* __restrict__ rowdiv, const float* __restrict__ coldiv,
               float* __restrict__ slot, int gx, int Nc, int K, int ldX, int sym)
{
  __shared__ unsigned short AB[3 * 8192];

  int orig = blockIdx.x;
  int bx, by;
  if (EPI == 2 && sym) {
    // 528 upper-tri tiles of a 32x32 grid; XCD-chunked bijective (528 = 8*66)
    int x = orig & 7, i = orig >> 3;
    int u = x * 66 + i;
    float disc = 4225.f - 8.f * (float)u;
    by = (int)((65.f - sqrtf(fmaxf(disc, 0.f))) * 0.5f);
    while (by > 0 && 32 * by - by * (by - 1) / 2 > u) by--;
    while (32 * (by + 1) - (by + 1) * by / 2 <= u) by++;
    bx = by + (u - (32 * by - by * (by - 1) / 2));
  } else {
    int x = orig & 7, tt = orig >> 3;
    bx = tt >> 2;
    by = x * 4 + (tt & 3);
  }
  const int row0 = by * 128, col0 = bx * 128;

  const int t = threadIdx.x, l = t & 63, wv = t >> 6;
  const int wr = wv >> 1, wc = wv & 1;
  const int lr = l & 15, lkh = (l >> 4) << 3;

  f32x4 acc[4][4];
  #pragma unroll
  for (int i = 0; i < 4; i++)
    #pragma unroll
    for (int j = 0; j < 4; j++) acc[i][j] = (f32x4){0.f, 0.f, 0.f, 0.f};

  const int srow = l >> 2;
  const int sk   = (l & 3) << 3;
  const unsigned short* Ab = A  + (size_t)(row0 + srow) * K + sk;
  const unsigned short* Bb = Bt + (size_t)(col0 + srow) * K + sk;

  const int NT = K >> 5;

  auto STAGE = [&](int kt, int buf) {
    unsigned short* As = AB + buf * 8192;
    unsigned short* Bs = As + 4096;
    int k0 = kt << 5;
    #pragma unroll
    for (int h2 = 0; h2 < 2; h2++) {
      int c = wv * 2 + h2;
      gload16(Ab + (size_t)c * 16 * K + k0, As + c * 512);
      gload16(Bb + (size_t)c * 16 * K + k0, Bs + c * 512);
    }
  };

  STAGE(0, 0);
  if (NT > 1) STAGE(1, 1);
  if (NT > 2) STAGE(2, 2);
  int cur = 0;

  for (int kt = 0; kt < NT; ++kt) {
    int ahead = NT - 1 - kt;
    if (ahead >= 2)      { VMW(8); }
    else if (ahead == 1) { VMW(4); }
    else                 { VMW(0); }
    __builtin_amdgcn_sched_barrier(0);
    __builtin_amdgcn_s_barrier();

    const unsigned short* As = AB + cur * 8192;
    const unsigned short* Bs = As + 4096;
    u16x8 af[4], bfv[4];
    #pragma unroll
    for (int mi = 0; mi < 4; mi++)
      af[mi] = *(const u16x8*)&As[(wr * 64 + mi * 16 + lr) * 32 + lkh];
    #pragma unroll
    for (int ni = 0; ni < 4; ni++)
      bfv[ni] = *(const u16x8*)&Bs[(wc * 64 + ni * 16 + lr) * 32 + lkh];
    #pragma unroll
    for (int mi = 0; mi < 4; mi++)
      #pragma unroll
      for (int ni = 0; ni < 4; ni++)
        acc[mi][ni] = __builtin_amdgcn_mfma_f32_16x16x32_bf16(
            __builtin_bit_cast(bf16x8, af[mi]),
            __builtin_bit_cast(bf16x8, bfv[ni]), acc[mi][ni], 0, 0, 0);

    __builtin_amdgcn_s_barrier();
    if (kt + 3 < NT) STAGE(kt + 3, cur);
    cur = (cur == 2) ? 0 : cur + 1;
  }

  const int lcol = l & 15, lrow = (l >> 4) << 2;
  if (EPI == 1) {
    #pragma unroll
    for (int mi = 0; mi < 4; mi++) {
      int rr = row0 + wr * 64 + mi * 16 + lrow;
      #pragma unroll
      for (int ni = 0; ni < 4; ni++) {
        int cc = col0 + wc * 64 + ni * 16 + lcol;
        #pragma unroll
        for (int r = 0; r < 4; r++)
          Cf[(size_t)(rr + r) * 4096 + cc] = acc[mi][ni][r];
      }
    }
  } else if (EPI == 2) {
    const float* Xf = (const float*)Xv;
    const unsigned short* Xh = (const unsigned short*)Xv;
    float part = 0.f;
    #pragma unroll
    for (int mi = 0; mi < 4; mi++) {
      int rr = row0 + wr * 64 + mi * 16 + lrow;
      #pragma unroll
      for (int ni = 0; ni < 4; ni++) {
        int cc = col0 + wc * 64 + ni * 16 + lcol;
        if (cc < Nc) {
          float cd = coldiv ? coldiv[cc] : 1.f;
          #pragma unroll
          for (int r = 0; r < 4; r++) {
            float v = acc[mi][ni][r];
            if (rowdiv) v /= rowdiv[rr + r];
            v /= cd;
            size_t xi = (size_t)(rr + r) * ldX + cc;
            float xval = XBF ? bf2f(Xh[xi]) : Xf[xi];
            float d = xval - v;
            part = fmaf(d, d, part);
          }
        }
      }
    }
    part = blk_red<false>(part);
    if (t == 0) {
      float wgt = (sym && col0 > row0) ? 2.f : 1.f;
      atomicAdd(slot, part * wgt);
    }
  } else { // EPI 3
    const unsigned short* Ph = (const unsigned short*)Xv;
    float a = 0.f, sp = 0.f;
    #pragma unroll
    for (int mi = 0; mi < 4; mi++) {
      int rr = row0 + wr * 64 + mi * 16 + lrow;
      #pragma unroll
      for (int ni = 0; ni < 4; ni++) {
        int cc = col0 + wc * 64 + ni * 16 + lcol;
        #pragma unroll
        for (int r = 0; r < 4; r++) {
          float g = acc[mi][ni][r];
          float p = bf2f(Ph[(size_t)(rr + r) * ldX + cc]);
          float d2 = rowdiv[rr + r] + coldiv[cc] - 2.f * g;
          a = fmaf(p, sqrtf(fmaxf(d2, 1e-12f)), a);
          sp = fmaf(p, logf(p + 1e-10f), sp);
        }
      }
    }
    a = blk_red<false>(a);
    sp = blk_red<false>(sp);
    if (t == 0) { atomicAdd(&slot[ALN], a); atomicAdd(&slot[SPS], sp); }
  }
}

// ============ narrow split-K bf16 MFMA: C[4096][Nc<=128] += A @ Bt^T ============
__global__ __launch_bounds__(256)
void ns_mfma_k(const unsigned short* __restrict__ A, const unsigned short* __restrict__ Bt,
               float* __restrict__ C, int Nc, int K, int KC, int ldC)
{
  __shared__ unsigned short AB[2 * 8192];
  int ks = blockIdx.x & 15, strip = blockIdx.x >> 4;
  const int row0 = strip * 128;
  const int kbase = ks * KC;

  const int t = threadIdx.x, l = t & 63, wv = t >> 6;
  const int wr = wv >> 1, wc = wv & 1;
  const int lr = l & 15, lkh = (l >> 4) << 3;

  f32x4 acc[4][4];
  #pragma unroll
  for (int i = 0; i < 4; i++)
    #pragma unroll
    for (int j = 0; j < 4; j++) acc[i][j] = (f32x4){0.f, 0.f, 0.f, 0.f};

  const int srow = l >> 2;
  const int sk   = (l & 3) << 3;
  const unsigned short* Ab = A  + (size_t)(row0 + srow) * K + kbase + sk;
  const unsigned short* Bb = Bt + (size_t)srow * K + kbase + sk;

  const int NT = KC >> 5;

  auto STAGE = [&](int kt, int buf) {
    unsigned short* As = AB + buf * 8192;
    unsigned short* Bs = As + 4096;
    int k0 = kt << 5;
    #pragma unroll
    for (int h2 = 0; h2 < 2; h2++) {
      int c = wv * 2 + h2;
      gload16(Ab + (size_t)c * 16 * K + k0, As + c * 512);
      gload16(Bb + (size_t)c * 16 * K + k0, Bs + c * 512);
    }
  };

  STAGE(0, 0);
  if (NT > 1) STAGE(1, 1);
  int cur = 0;

  for (int kt = 0; kt < NT; ++kt) {
    if (kt + 1 < NT) { VMW(4); }
    else             { VMW(0); }
    __builtin_amdgcn_sched_barrier(0);
    __builtin_amdgcn_s_barrier();

    const unsigned short* As = AB + cur * 8192;
    const unsigned short* Bs = As + 4096;
    u16x8 af[4], bfv[4];
    #pragma unroll
    for (int mi = 0; mi < 4; mi++)
      af[mi] = *(const u16x8*)&As[(wr * 64 + mi * 16 + lr) * 32 + lkh];
    #pragma unroll
    for (int ni = 0; ni < 4; ni++)
      bfv[ni] = *(const u16x8*)&Bs[(wc * 64 + ni * 16 + lr) * 32 + lkh];
    #pragma unroll
    for (int mi = 0; mi < 4; mi++)
      #pragma unroll
      for (int ni = 0; ni < 4; ni++)
        acc[mi][ni] = __builtin_amdgcn_mfma_f32_16x16x32_bf16(
            __builtin_bit_cast(bf16x8, af[mi]),
            __builtin_bit_cast(bf16x8, bfv[ni]), acc[mi][ni], 0, 0, 0);

    __builtin_amdgcn_s_barrier();
    if (kt + 2 < NT) STAGE(kt + 2, cur);
    cur ^= 1;
  }

  const int lcol = l & 15, lrow = (l >> 4) << 2;
  #pragma unroll
  for (int mi = 0; mi < 4; mi++) {
    int rr = row0 + wr * 64 + mi * 16 + lrow;
    #pragma unroll
    for (int ni = 0; ni < 4; ni++) {
      int cc = wc * 64 + ni * 16 + lcol;
      if (cc < Nc) {
        #pragma unroll
        for (int r = 0; r < 4; r++)
          atomicAdd(&C[(size_t)(rr + r) * ldC + cc], acc[mi][ni][r]);
      }
    }
  }
}

// ---------------- conversion / transpose pre-passes ----------------
__global__ void cvt_k(const float* __restrict__ s, unsigned short* __restrict__ d,
                      int n8, float scale)
{
  int i = blockIdx.x * 256 + threadIdx.x;
  if (i < n8) {
    float4 a = ((const float4*)s)[2 * i], b = ((const float4*)s)[2 * i + 1];
    u16x8 w;
    w[0] = f2bf(a.x * scale); w[1] = f2bf(a.y * scale);
    w[2] = f2bf(a.z * scale); w[3] = f2bf(a.w * scale);
    w[4] = f2bf(b.x * scale); w[5] = f2bf(b.y * scale);
    w[6] = f2bf(b.z * scale); w[7] = f2bf(b.w * scale);
    ((u16x8*)d)[i] = w;
  }
}

// msk [4096][4096] fp32 -> bf16 + fused row sums (mrs pre-zeroed). grid 8192
__global__ void cvt_rs_k(const float* __restrict__ s, unsigned short* __restrict__ d,
                         float* __restrict__ mrs)
{
  int i = blockIdx.x * 256 + threadIdx.x;    // chunk of 8 elems, 512 chunks/row
  float4 a = ((const float4*)s)[2 * i], b = ((const float4*)s)[2 * i + 1];
  u16x8 w;
  w[0] = f2bf(a.x); w[1] = f2bf(a.y); w[2] = f2bf(a.z); w[3] = f2bf(a.w);
  w[4] = f2bf(b.x); w[5] = f2bf(b.y); w[6] = f2bf(b.z); w[7] = f2bf(b.w);
  ((u16x8*)d)[i] = w;
  float s8 = a.x + a.y + a.z + a.w + b.x + b.y + b.z + b.w;
  float ws = wave_red_sum(s8);
  if ((threadIdx.x & 63) == 0) atomicAdd(&mrs[i >> 9], ws);
}

// [4096][3000] fp32 -> [4096][3072] bf16 zero-padded
__global__ void cvt_pad_k(const float* __restrict__ s, unsigned short* __restrict__ d)
{
  int i = blockIdx.x * 256 + threadIdx.x;
  int row = i / 384, c8 = (i - row * 384) * 8;
  u16x8 w = (u16x8)0;
  if (c8 < kIN) {
    const float* sp = s + (size_t)row * kIN + c8;
    float4 a = *(const float4*)sp, b = *(const float4*)(sp + 4);
    w[0] = f2bf(a.x); w[1] = f2bf(a.y); w[2] = f2bf(a.z); w[3] = f2bf(a.w);
    w[4] = f2bf(b.x); w[5] = f2bf(b.y); w[6] = f2bf(b.z); w[7] = f2bf(b.w);
  }
  ((u16x8*)d)[i] = w;
}

// [4096][128] fp32 cols 0..63 -> [4096][64] bf16
__global__ void cvt_cols_k(const float* __restrict__ s, unsigned short* __restrict__ d)
{
  int i = blockIdx.x * 256 + threadIdx.x;
  int row = i >> 3, c8 = (i & 7) * 8;
  const float* sp = s + (size_t)row * 128 + c8;
  float4 a = *(const float4*)sp, b = *(const float4*)(sp + 4);
  u16x8 w;
  w[0] = f2bf(a.x); w[1] = f2bf(a.y); w[2] = f2bf(a.z); w[3] = f2bf(a.w);
  w[4] = f2bf(b.x); w[5] = f2bf(b.y); w[6] = f2bf(b.z); w[7] = f2bf(b.w);
  ((u16x8*)d)[i] = w;
}

// transpose+convert: src fp32 [R][C] (ld sld) -> dst bf16 (ld dld), optional relu
template<bool RELU>
__global__ void tr_k(const float* __restrict__ src, unsigned short* __restrict__ dst,
                     int R, int C, int sld, int dld)
{
  __shared__ float tile[32][33];
  int c0 = blockIdx.x * 32, r0 = blockIdx.y * 32;
  int tr_ = threadIdx.x >> 3, tc4 = (threadIdx.x & 7) << 2;
  #pragma unroll
  for (int j = 0; j < 4; j++) {
    int r = r0 + tr_, c = c0 + tc4 + j;
    float v = (r < R && c < C) ? src[(size_t)r * sld + c] : 0.f;
    if (RELU) v = fmaxf(v, 0.f);
    tile[tr_][tc4 + j] = v;
  }
  __syncthreads();
  u16x4 wv;
  #pragma unroll
  for (int j = 0; j < 4; j++) wv[j] = f2bf(tile[tc4 + j][tr_]);
  *(u16x4*)&dst[(size_t)(c0 + tr_) * dld + r0 + tc4] = wv;
}

// ---------------- small fp32 GEMM (64-col weight GEMMs only) ----------------
__global__ __launch_bounds__(256)
void gemm_small_k(const float* __restrict__ A, const float* __restrict__ B,
                  float* __restrict__ C, int M, int Nc, int K,
                  int ldA, int ldB, int ldC)
{
  __shared__ float As[16][68];
  __shared__ float Bs[16][68];
  int tid = threadIdx.x;
  int tx = tid & 15, ty = tid >> 4;
  int row0 = blockIdx.y * 64, col0 = blockIdx.x * 64;
  float acc[4][4] = {};

  for (int k0 = 0; k0 < K; k0 += 16) {
    {
      int m = tid >> 2, kk = (tid & 3) << 2;
      const float* ap = A + (size_t)(row0 + m) * ldA + k0 + kk;
      float4 v = *(const float4*)ap;
      As[kk + 0][m] = v.x; As[kk + 1][m] = v.y; As[kk + 2][m] = v.z; As[kk + 3][m] = v.w;
    }
    {
      int kk = tid >> 4, c = (tid & 15) << 2;
      const float* bp = B + (size_t)(k0 + kk) * ldB + col0 + c;
      #pragma unroll
      for (int i = 0; i < 4; i++)
        Bs[kk][c + i] = (col0 + c + i < Nc) ? bp[i] : 0.f;
    }
    __syncthreads();
    #pragma unroll
    for (int kk = 0; kk < 16; kk++) {
      float4 a4 = *(const float4*)&As[kk][ty << 2];
      float4 b4 = *(const float4*)&Bs[kk][tx << 2];
      float av[4] = {a4.x, a4.y, a4.z, a4.w};
      float bv[4] = {b4.x, b4.y, b4.z, b4.w};
      #pragma unroll
      for (int i = 0; i < 4; i++)
        #pragma unroll
        for (int j = 0; j < 4; j++)
          acc[i][j] = fmaf(av[i], bv[j], acc[i][j]);
    }
    __syncthreads();
  }
  #pragma unroll
  for (int i = 0; i < 4; i++) {
    int r = row0 + (ty << 2) + i;
    #pragma unroll
    for (int j = 0; j < 4; j++) {
      int c = col0 + (tx << 2) + j;
      if (c < Nc) C[(size_t)r * ldC + c] = acc[i][j];
    }
  }
}

// ---------------- fused Sinkhorn passes ----------------
__global__ __launch_bounds__(256)
void sink_k(float* __restrict__ P, unsigned short* __restrict__ Pb,
            const float* __restrict__ cs_in, float* __restrict__ cs_out,
            float* __restrict__ rs, int mode)
{
  int tid = threadIdx.x;
  int r0 = blockIdx.x * 8;
  float csl[16] = {};
  float cdiv[16];
  if (mode != 0) {
    #pragma unroll
    for (int t = 0; t < 4; t++) {
      float4 c4 = ((const float4*)cs_in)[tid + t * 256];
      cdiv[4 * t + 0] = 1.f / (4096.f * c4.x);
      cdiv[4 * t + 1] = 1.f / (4096.f * c4.y);
      cdiv[4 * t + 2] = 1.f / (4096.f * c4.z);
      cdiv[4 * t + 3] = 1.f / (4096.f * c4.w);
    }
  }
  for (int rr = 0; rr < 8; rr++) {
    int row = r0 + rr;
    float4* prow = (float4*)(P + (size_t)row * 4096);
    float4 r[4];
    #pragma unroll
    for (int t = 0; t < 4; t++) r[t] = prow[tid + t * 256];

    if (mode == 0) {
      float m = -3.4e38f;
      #pragma unroll
      for (int t = 0; t < 4; t++)
        m = fmaxf(m, fmaxf(fmaxf(r[t].x, r[t].y), fmaxf(r[t].z, r[t].w)));
      m = blk_red<true>(m);
      float s = 0.f;
      #pragma unroll
      for (int t = 0; t < 4; t++) {
        r[t].x = expf(r[t].x - m); r[t].y = expf(r[t].y - m);
        r[t].z = expf(r[t].z - m); r[t].w = expf(r[t].w - m);
        s += r[t].x + r[t].y + r[t].z + r[t].w;
      }
      s = blk_red<false>(s);
      float f = 1.f / (s * 4096.f);
      #pragma unroll
      for (int t = 0; t < 4; t++) {
        r[t].x *= f; r[t].y *= f; r[t].z *= f; r[t].w *= f;
        prow[tid + t * 256] = r[t];
        csl[4 * t + 0] += r[t].x; csl[4 * t + 1] += r[t].y;
        csl[4 * t + 2] += r[t].z; csl[4 * t + 3] += r[t].w;
      }
    } else {
      float s = 0.f;
      #pragma unroll
      for (int t = 0; t < 4; t++) {
        r[t].x *= cdiv[4 * t + 0]; r[t].y *= cdiv[4 * t + 1];
        r[t].z *= cdiv[4 * t + 2]; r[t].w *= cdiv[4 * t + 3];
        s += r[t].x + r[t].y + r[t].z + r[t].w;
      }
      s = blk_red<false>(s);
      if (mode == 1) {
        float f = 1.f / (4096.f * s);
        #pragma unroll
        for (int t = 0; t < 4; t++) {
          r[t].x *= f; r[t].y *= f; r[t].z *= f; r[t].w *= f;
          prow[tid + t * 256] = r[t];
          csl[4 * t + 0] += r[t].x; csl[4 * t + 1] += r[t].y;
          csl[4 * t + 2] += r[t].z; csl[4 * t + 3] += r[t].w;
        }
      } else {
        if (tid == 0) rs[row] = s;
        #pragma unroll
        for (int t = 0; t < 4; t++) {
          prow[tid + t * 256] = r[t];
          u16x4 w;
          w[0] = f2bf(r[t].x); w[1] = f2bf(r[t].y);
          w[2] = f2bf(r[t].z); w[3] = f2bf(r[t].w);
          *(u16x4*)&Pb[(size_t)row * 4096 + 4 * (tid + t * 256)] = w;
          csl[4 * t + 0] += r[t].x; csl[4 * t + 1] += r[t].y;
          csl[4 * t + 2] += r[t].z; csl[4 * t + 3] += r[t].w;
        }
      }
    }
  }
  #pragma unroll
  for (int t = 0; t < 4; t++) {
    int j = 4 * (tid + t * 256);
    atomicAdd(&cs_out[j + 0], csl[4 * t + 0]);
    atomicAdd(&cs_out[j + 1], csl[4 * t + 1]);
    atomicAdd(&cs_out[j + 2], csl[4 * t + 2]);
    atomicAdd(&cs_out[j + 3], csl[4 * t + 3]);
  }
}

__global__ void relu_k(const float* __restrict__ in, float* __restrict__ out, int n)
{
  int i = blockIdx.x * blockDim.x + threadIdx.x;
  if (i < n) out[i] = fmaxf(in[i], 0.f);
}

__global__ void gather_k(float* __restrict__ XP, const int* __restrict__ perm)
{
  int gid = blockIdx.x * 256 + threadIdx.x;
  int i = gid >> 6, j = gid & 63;
  XP[(size_t)i * 128 + 64 + j] = XP[(size_t)perm[i] * 128 + j];
}

__global__ void sqnorm_k(const float* __restrict__ H, int ld, float* __restrict__ outv)
{
  int gid = blockIdx.x * 256 + threadIdx.x;
  int row = gid >> 6, j = gid & 63;
  float v = H[(size_t)row * ld + j];
  float p = wave_red_sum(v * v);
  if (j == 0) outv[row] = p;
}

__global__ void readout_k(const float* __restrict__ vs2, const float* __restrict__ mrs,
                          float* __restrict__ g2)
{
  int q = blockIdx.x, j = threadIdx.x;
  float v = vs2[(size_t)q * 64 + j] / mrs[q >> 1];
  float p = v * v;
  #pragma unroll
  for (int s = 1; s < 64; s <<= 1) p += __shfl_xor(p, s, 64);
  float nrm = sqrtf(p);
  v = v / fmaxf(nrm, 1e-12f);
  g2[(size_t)q * 64 + j] = 1.f / (1.f + expf(-v));
}

__device__ __forceinline__ float bce_term(float x, float y) {
  return fmaxf(x, 0.f) - x * y + log1pf(expf(-fabsf(x)));
}

__global__ void disc_k(const float* __restrict__ G2, const float* __restrict__ W2,
                       const float* __restrict__ lab, const float* __restrict__ bptr,
                       float* __restrict__ acc)
{
  int i = blockIdx.x, j = threadIdx.x;
  float gj  = G2[(size_t)(2 * i) * 64 + j];
  float gaj = G2[(size_t)(2 * i + 1) * 64 + j];
  float hw  = W2[(size_t)(2 * i) * 64 + j];
  float haw = W2[(size_t)(2 * i + 1) * 64 + j];
  float s1 = hw * gj, s2 = haw * gj, s1a = haw * gaj, s2a = hw * gaj;
  #pragma unroll
  for (int s = 1; s < 64; s <<= 1) {
    s1  += __shfl_xor(s1, s, 64);
    s2  += __shfl_xor(s2, s, 64);
    s1a += __shfl_xor(s1a, s, 64);
    s2a += __shfl_xor(s2a, s, 64);
  }
  if (j == 0) {
    float b = bptr[0];
    float y0 = lab[i * 2 + 0], y1 = lab[i * 2 + 1];
    float t = bce_term(s1 + b, y0) + bce_term(s2 + b, y1)
            + bce_term(s1a + b, y0) + bce_term(s2a + b, y1);
    atomicAdd(&acc[SL], t);
  }
}

__global__ __launch_bounds__(256)
void finalize_k(const float* __restrict__ acc, const float* __restrict__ cs,
                float* __restrict__ out)
{
  int tid = threadIdx.x;
  float invm2 = 1.f / (float)kN;
  float t = 0.f;
  for (int j = tid; j < kN; j += 256) {
    float q = cs[j];
    t += q * (logf(q) - invm2);
  }
  t = blk_red<false>(t);
  if (tid == 0) {
    float kld_pq = t * invm2;
    float kld_pp = invm2 * (logf(invm2) - invm2);
    out[0] = acc[SL] / (2.f * (float)kN);
    out[1] = acc[FEAT] / ((float)kN * (float)kIN);
    out[2] = acc[ALN];
    out[3] = (acc[FXA] + acc[FXB]) / ((float)kN * (float)kIN);
    out[4] = sqrtf(acc[SM1]) / (float)kN + sqrtf(acc[SM2]) / (float)kN;
    out[5] = (kld_pq - kld_pp) * (float)kN;
    out[6] = -acc[SPS];
  }
}

extern "C" void kernel_launch(void* const* d_in, const int* in_sizes, int n_in,
                              void* d_out, int out_size, void* d_ws, size_t ws_size,
                              hipStream_t stream)
{
  (void)in_sizes; (void)n_in; (void)out_size; (void)ws_size;
  const float* feat  = (const float*)d_in[0];
  const float* adjs  = (const float*)d_in[1];
  const float* gmask = (const float*)d_in[2];
  const float* labs  = (const float*)d_in[3];
  const float* dists = (const float*)d_in[4];
  const int*   perms = (const int*)d_in[5];
  const float* encW  = (const float*)d_in[6];
  const float* decW  = (const float*)d_in[7];
  const float* MsW   = (const float*)d_in[8];
  const float* discW = (const float*)d_in[9];
  const float* discb = (const float*)d_in[10];
  float* out = (float*)d_out;

  const size_t SZNN = (size_t)kN * kN;

  char* cur = (char*)d_ws;
  auto alloc = [&](size_t bytes) {
    char* p = cur;
    cur += (bytes + 255) & ~(size_t)255;
    return p;
  };
  float* P            = (float*)alloc(SZNN * 4);          // fp32 P; later reused for Tb
  unsigned short* Pb  = (unsigned short*)alloc(SZNN * 2);
  unsigned short* PbT = (unsigned short*)alloc(SZNN * 2);
  unsigned short* Db  = (unsigned short*)alloc(SZNN * 2);
  unsigned short* ajb = (unsigned short*)alloc(SZNN * 2); // adj/msk bf16; later ftb
  unsigned short* xb  = (unsigned short*)alloc((size_t)kN * kINp * 2);
  unsigned short* dWtb= (unsigned short*)alloc((size_t)kINp * kLAT * 2);
  unsigned short* ahb = (unsigned short*)alloc((size_t)kN * kLAT * 2);
  unsigned short* encWtp = (unsigned short*)alloc((size_t)128 * kINp * 2);
  unsigned short* XPt = (unsigned short*)alloc((size_t)128 * kN * 2);
  unsigned short* hbTp= (unsigned short*)alloc((size_t)128 * kN * 2);
  unsigned short* HRt = (unsigned short*)alloc((size_t)128 * kN * 2);
  unsigned short* smb = (unsigned short*)alloc((size_t)kN * kLAT * 2);
  unsigned short* tmb = (unsigned short*)alloc((size_t)kN * kLAT * 2);
  unsigned short* h0b = (unsigned short*)alloc((size_t)kN * kLAT * 2);
  unsigned short* h1b = (unsigned short*)alloc((size_t)kN * kLAT * 2);
  float* XP  = (float*)alloc((size_t)kN * 128 * 4);
  float* HH0 = (float*)alloc((size_t)kN * 128 * 4);
  float* HH1 = (float*)alloc((size_t)kN * 128 * 4);
  float* HR  = (float*)alloc((size_t)kN * 128 * 4);
  float* VS  = (float*)alloc((size_t)kN * 128 * 4);
  float* G2  = (float*)alloc((size_t)kN * 128 * 4);
  float* W2  = (float*)alloc((size_t)kN * 128 * 4);
  float* SM_ = (float*)alloc((size_t)kN * kLAT * 4);
  float* TM_ = (float*)alloc((size_t)kN * kLAT * 4);
  float* ah  = (float*)alloc((size_t)kN * kLAT * 4);
  float* sns = (float*)alloc(kN * 4);
  float* snt = (float*)alloc(kN * 4);
  float* rs  = (float*)alloc(kN * 4);
  float* cs  = (float*)alloc(kN * 4);
  float* csA = (float*)alloc(kN * 4);
  float* csB = (float*)alloc(kN * 4);
  float* mrs = (float*)alloc(kN * 4);
  float* acc = (float*)alloc(NSLOT * 4);

  unsigned short* Tb  = (unsigned short*)P;     // alias: fp32 P dead before Tb written
  unsigned short* ftb = ajb;                    // alias: adj/msk bf16 dead after slices

  hipMemsetAsync(acc, 0, NSLOT * sizeof(float), stream);

  // ---------------- per-slice losses ----------------
  for (int k = 0; k < 2; k++) {
    const float* x    = feat  + (size_t)k * kN * kIN;
    const float* adj  = adjs  + (size_t)k * SZNN;
    const float* msk  = gmask + (size_t)k * SZNN;
    const float* lab  = labs  + (size_t)k * kN * 2;
    const int*   perm = perms + (size_t)k * kN;
    const float* eW   = encW  + (size_t)k * kIN * kLAT;
    const float* dW   = decW  + (size_t)k * kLAT * kIN;
    float* HHk = (k == 0) ? HH0 : HH1;

    cvt_pad_k<<<6144, 256, 0, stream>>>(x, xb);
    hipMemsetAsync(encWtp, 0, (size_t)128 * kINp * 2, stream);
    tr_k<false><<<dim3(2, (kIN + 31) / 32), 256, 0, stream>>>(eW, encWtp, kIN, kLAT, kLAT, kINp);
    hipMemsetAsync(XP, 0, (size_t)kN * 128 * 4, stream);
    ns_mfma_k<<<512, 256, 0, stream>>>(xb, encWtp, XP, kLAT, kINp, kINp / 16, 128);
    gather_k<<<kN * 64 / 256, 256, 0, stream>>>(XP, perm);
    tr_k<false><<<dim3(4, 128), 256, 0, stream>>>(XP, XPt, kN, 128, 128, kN);
    cvt_k<<<(int)(SZNN / 8 / 256), 256, 0, stream>>>(adj, ajb, (int)(SZNN / 8), 1.f);
    hipMemsetAsync(HHk, 0, (size_t)kN * 128 * 4, stream);
    ns_mfma_k<<<512, 256, 0, stream>>>(ajb, XPt, HHk, 128, kN, kN / 16, 128);
    hipMemsetAsync(hbTp, 0, (size_t)128 * kN * 2, stream);
    tr_k<false><<<dim3(2, 128), 256, 0, stream>>>(HHk, hbTp, kN, kLAT, 128, kN);
    hipMemsetAsync(ah, 0, (size_t)kN * kLAT * 4, stream);
    ns_mfma_k<<<512, 256, 0, stream>>>(ajb, hbTp, ah, kLAT, kN, kN / 16, kLAT);
    cvt_k<<<128, 256, 0, stream>>>(ah, ahb, kN * kLAT / 8, 1.f);
    tr_k<false><<<dim3(kINp / 32, 2), 256, 0, stream>>>(dW, dWtb, kLAT, kIN, kIN, kLAT);
    bt_mfma_k<2, 1><<<(kINp / 128) * 32, 256, 0, stream>>>(
        ahb, dWtb, nullptr, nullptr, xb, nullptr, nullptr, &acc[FEAT],
        kINp / 128, kIN, kLAT, kINp, 0);
    relu_k<<<kN * 128 / 256, 256, 0, stream>>>(HHk, HR, kN * 128);
    tr_k<true><<<dim3(4, 128), 256, 0, stream>>>(HHk, HRt, kN, 128, 128, kN);
    hipMemsetAsync(mrs, 0, kN * 4, stream);
    cvt_rs_k<<<(int)(SZNN / 8 / 256), 256, 0, stream>>>(msk, ajb, mrs);
    hipMemsetAsync(VS, 0, (size_t)kN * 128 * 4, stream);
    ns_mfma_k<<<512, 256, 0, stream>>>(ajb, HRt, VS, 128, kN, kN / 16, 128);
    readout_k<<<2 * kN, 64, 0, stream>>>(VS, mrs, G2);
    gemm_small_k<<<dim3(1, 128), 256, 0, stream>>>(HR, discW, W2, 2 * kN, kLAT, kLAT,
                                                   kLAT, kLAT, kLAT);
    disc_k<<<kN, 64, 0, stream>>>(G2, W2, lab, discb, acc);
  }

  // ---------------- alignment losses ----------------
  const float* f0 = feat;
  const float* f1 = feat + (size_t)kN * kIN;
  const float* D0 = dists;
  const float* D1 = dists + SZNN;

  gemm_small_k<<<dim3(1, 64), 256, 0, stream>>>(HH0, MsW, SM_, kN, kLAT, kLAT, 128, kLAT, kLAT);
  gemm_small_k<<<dim3(1, 64), 256, 0, stream>>>(HH1, MsW, TM_, kN, kLAT, kLAT, 128, kLAT, kLAT);
  cvt_k<<<128, 256, 0, stream>>>(SM_, smb, kN * kLAT / 8, 0.125f);
  cvt_k<<<128, 256, 0, stream>>>(TM_, tmb, kN * kLAT / 8, 1.f);
  // P = srcM @ tgtM^T / 8  (128-tile MFMA, fp32 store)
  bt_mfma_k<1, 0><<<1024, 256, 0, stream>>>(smb, tmb, nullptr, P, nullptr, nullptr, nullptr,
                                            nullptr, 32, kN, kLAT, 0, 0);

  // fused sinkhorn: softmax + 3 iters + final marginals + bf16 P, 4 passes
  hipMemsetAsync(csA, 0, kN * 4, stream);
  sink_k<<<512, 256, 0, stream>>>(P, nullptr, nullptr, csA, nullptr, 0);
  hipMemsetAsync(csB, 0, kN * 4, stream);
  sink_k<<<512, 256, 0, stream>>>(P, nullptr, csA, csB, nullptr, 1);
  hipMemsetAsync(csA, 0, kN * 4, stream);
  sink_k<<<512, 256, 0, stream>>>(P, nullptr, csB, csA, nullptr, 1);
  hipMemsetAsync(cs, 0, kN * 4, stream);
  sink_k<<<512, 256, 0, stream>>>(P, Pb, csA, cs, rs, 2);

  // PbT = bf16(P^T) — last read of fp32 P
  tr_k<false><<<dim3(kN / 32, kN / 32), 256, 0, stream>>>(P, PbT, kN, kN, kN, kN);

  // align + sparsity: h0@h1^T (128-tile MFMA, EPI3)
  cvt_cols_k<<<128, 256, 0, stream>>>(HH0, h0b);
  cvt_cols_k<<<128, 256, 0, stream>>>(HH1, h1b);
  sqnorm_k<<<kN * 64 / 256, 256, 0, stream>>>(HH0, 128, sns);
  sqnorm_k<<<kN * 64 / 256, 256, 0, stream>>>(HH1, 128, snt);
  bt_mfma_k<3, 1><<<1024, 256, 0, stream>>>(h0b, h1b, nullptr, nullptr, Pb, sns, snt, acc,
                                            32, kN, kLAT, kN, 0);

  // loss_align_fix (128-tile bt, 768 blocks — full grid fill)
  tr_k<false><<<dim3(kINp / 32, kN / 32), 256, 0, stream>>>(f1, ftb, kN, kIN, kIN, kN);
  bt_mfma_k<2, 0><<<(kINp / 128) * 32, 256, 0, stream>>>(
      Pb, ftb, nullptr, nullptr, f0, rs, nullptr, &acc[FXA], kINp / 128, kIN, kN, kIN, 0);
  tr_k<false><<<dim3(kINp / 32, kN / 32), 256, 0, stream>>>(f0, ftb, kN, kIN, kIN, kN);
  bt_mfma_k<2, 0><<<(kINp / 128) * 32, 256, 0, stream>>>(
      PbT, ftb, nullptr, nullptr, f1, cs, nullptr, &acc[FXB], kINp / 128, kIN, kN, kIN, 0);

  // loss_maintain 1: Tb = (P@D1)/rs (g8 dense) ; SM1 = sum((D0 - (Tb@P^T)/rs)^2) sym (bt)
  cvt_k<<<(int)(SZNN / 8 / 256), 256, 0, stream>>>(D1, Db, (int)(SZNN / 8), 1.f);
  g8_mfma_k<<<256, 512, 0, stream>>>(Pb, Db, Tb, rs, kN);
  bt_mfma_k<2, 0><<<528, 256, 0, stream>>>(Tb, Pb, nullptr, nullptr, D0, nullptr, rs,
                                           &acc[SM1], 32, kN, kN, kN, 1);
  // loss_maintain 2: Tb = (P^T@D0)/cs (g8 dense) ; SM2 = sum((D1 - (Tb@P)/cs)^2) sym (bt)
  cvt_k<<<(int)(SZNN / 8 / 256), 256, 0, stream>>>(D0, Db, (int)(SZNN / 8), 1.f);
  g8_mfma_k<<<256, 512, 0, stream>>>(PbT, Db, Tb, cs, kN);
  bt_mfma_k<2, 0><<<528, 256, 0, stream>>>(Tb, PbT, nullptr, nullptr, D1, nullptr, cs,
                                           &acc[SM2], 32, kN, kN, kN, 1);

  finalize_k<<<1, 256, 0, stream>>>(acc, cs, out);
}

// Round 9
// 1981.214 us; speedup vs baseline: 1.0610x; 1.0353x over previous
//
#include <hip/hip_runtime.h>
#include <cmath>

// Problem constants
constexpr int kN   = 4096;
constexpr int kIN  = 3000;
constexpr int kINp = 3072;   // kIN padded to 128-multiple
constexpr int kLAT = 64;

enum { SL = 0, FEAT, ALN, FXA, FXB, SM1, SM2, SPS, NSLOT };

typedef __bf16 bf16x8 __attribute__((ext_vector_type(8)));
typedef float f32x4 __attribute__((ext_vector_type(4)));
typedef unsigned short u16x8 __attribute__((ext_vector_type(8)));
typedef unsigned short u16x4 __attribute__((ext_vector_type(4)));

// ---------------- reduction helpers ----------------
template<bool IS_MAX>
__device__ __forceinline__ float blk_red(float v) {
  __shared__ float buf[8];
  #pragma unroll
  for (int s = 32; s > 0; s >>= 1) {
    float o = __shfl_down(v, s, 64);
    v = IS_MAX ? fmaxf(v, o) : (v + o);
  }
  int lane = threadIdx.x & 63, wv = threadIdx.x >> 6, nw = blockDim.x >> 6;
  __syncthreads();
  if (lane == 0) buf[wv] = v;
  __syncthreads();
  float r = buf[0];
  for (int i = 1; i < nw; i++) r = IS_MAX ? fmaxf(r, buf[i]) : (r + buf[i]);
  return r;
}

__device__ __forceinline__ float wave_red_sum(float v) {
  #pragma unroll
  for (int s = 32; s > 0; s >>= 1) v += __shfl_down(v, s, 64);
  return v;
}

// fp32 -> bf16 RNE ; bf16 -> fp32
__device__ __forceinline__ unsigned short f2bf(float f) {
  unsigned u = __builtin_bit_cast(unsigned, f);
  u += 0x7fffu + ((u >> 16) & 1u);
  return (unsigned short)(u >> 16);
}
__device__ __forceinline__ float bf2f(unsigned short h) {
  return __builtin_bit_cast(float, (unsigned)h << 16);
}

// async global->LDS, 16B per lane
__device__ __forceinline__ void gload16(const unsigned short* g, unsigned short* l) {
  __builtin_amdgcn_global_load_lds(
      (const __attribute__((address_space(1))) unsigned int*)g,
      (__attribute__((address_space(3))) unsigned int*)l, 16, 0, 0);
}

#define VMW(n) asm volatile("s_waitcnt vmcnt(" #n ")" ::: "memory")

// ================== 128-tile bf16 MFMA GEMM: C = A @ Bt^T ==================
// 3-deep pipeline, counted vmcnt. Dense strip decode or sym triangular (528).
// EPI 0: Cb = bf16(acc / rowdiv[r])
// EPI 1: Cf = acc (fp32)
// EPI 2: slot += wgt*sum (X - acc/rd/cd)^2 (X fp32 XBF=0 / bf16 XBF=1)
// EPI 3: align+sparsity epilogue
template<int EPI, int XBF>
__global__ __launch_bounds__(256)
void bt_mfma_k(const unsigned short* __restrict__ A, const unsigned short* __restrict__ Bt,
               unsigned short* __restrict__ Cb, float* __restrict__ Cf,
               const void* __restrict__ Xv,
               const float* __restrict__ rowdiv, const float* __restrict__ coldiv,
               float* __restrict__ slot, int gx, int Nc, int K, int ldX, int sym)
{
  __shared__ unsigned short AB[3 * 8192];

  int orig = blockIdx.x;
  int bx, by;
  if (EPI == 2 && sym) {
    // 528 upper-tri tiles of a 32x32 grid; XCD-chunked bijective (528 = 8*66)
    int x = orig & 7, i = orig >> 3;
    int u = x * 66 + i;
    float disc = 4225.f - 8.f * (float)u;
    by = (int)((65.f - sqrtf(fmaxf(disc, 0.f))) * 0.5f);
    while (by > 0 && 32 * by - by * (by - 1) / 2 > u) by--;
    while (32 * (by + 1) - (by + 1) * by / 2 <= u) by++;
    bx = by + (u - (32 * by - by * (by - 1) / 2));
  } else {
    int x = orig & 7, tt = orig >> 3;
    bx = tt >> 2;
    by = x * 4 + (tt & 3);
  }
  const int row0 = by * 128, col0 = bx * 128;

  const int t = threadIdx.x, l = t & 63, wv = t >> 6;
  const int wr = wv >> 1, wc = wv & 1;
  const int lr = l & 15, lkh = (l >> 4) << 3;

  f32x4 acc[4][4];
  #pragma unroll
  for (int i = 0; i < 4; i++)
    #pragma unroll
    for (int j = 0; j < 4; j++) acc[i][j] = (f32x4){0.f, 0.f, 0.f, 0.f};

  const int srow = l >> 2;
  const int sk   = (l & 3) << 3;
  const unsigned short* Ab = A  + (size_t)(row0 + srow) * K + sk;
  const unsigned short* Bb = Bt + (size_t)(col0 + srow) * K + sk;

  const int NT = K >> 5;

  auto STAGE = [&](int kt, int buf) {
    unsigned short* As = AB + buf * 8192;
    unsigned short* Bs = As + 4096;
    int k0 = kt << 5;
    #pragma unroll
    for (int h2 = 0; h2 < 2; h2++) {
      int c = wv * 2 + h2;
      gload16(Ab + (size_t)c * 16 * K + k0, As + c * 512);
      gload16(Bb + (size_t)c * 16 * K + k0, Bs + c * 512);
    }
  };

  STAGE(0, 0);
  if (NT > 1) STAGE(1, 1);
  if (NT > 2) STAGE(2, 2);
  int cur = 0;

  for (int kt = 0; kt < NT; ++kt) {
    int ahead = NT - 1 - kt;
    if (ahead >= 2)      { VMW(8); }
    else if (ahead == 1) { VMW(4); }
    else                 { VMW(0); }
    __builtin_amdgcn_sched_barrier(0);
    __builtin_amdgcn_s_barrier();

    const unsigned short* As = AB + cur * 8192;
    const unsigned short* Bs = As + 4096;
    u16x8 af[4], bfv[4];
    #pragma unroll
    for (int mi = 0; mi < 4; mi++)
      af[mi] = *(const u16x8*)&As[(wr * 64 + mi * 16 + lr) * 32 + lkh];
    #pragma unroll
    for (int ni = 0; ni < 4; ni++)
      bfv[ni] = *(const u16x8*)&Bs[(wc * 64 + ni * 16 + lr) * 32 + lkh];
    #pragma unroll
    for (int mi = 0; mi < 4; mi++)
      #pragma unroll
      for (int ni = 0; ni < 4; ni++)
        acc[mi][ni] = __builtin_amdgcn_mfma_f32_16x16x32_bf16(
            __builtin_bit_cast(bf16x8, af[mi]),
            __builtin_bit_cast(bf16x8, bfv[ni]), acc[mi][ni], 0, 0, 0);

    __builtin_amdgcn_s_barrier();
    if (kt + 3 < NT) STAGE(kt + 3, cur);
    cur = (cur == 2) ? 0 : cur + 1;
  }

  const int lcol = l & 15, lrow = (l >> 4) << 2;
  if (EPI == 0) {
    #pragma unroll
    for (int mi = 0; mi < 4; mi++) {
      int rr = row0 + wr * 64 + mi * 16 + lrow;
      #pragma unroll
      for (int ni = 0; ni < 4; ni++) {
        int cc = col0 + wc * 64 + ni * 16 + lcol;
        #pragma unroll
        for (int r = 0; r < 4; r++) {
          float v = acc[mi][ni][r];
          if (rowdiv) v /= rowdiv[rr + r];
          Cb[(size_t)(rr + r) * 4096 + cc] = f2bf(v);
        }
      }
    }
  } else if (EPI == 1) {
    #pragma unroll
    for (int mi = 0; mi < 4; mi++) {
      int rr = row0 + wr * 64 + mi * 16 + lrow;
      #pragma unroll
      for (int ni = 0; ni < 4; ni++) {
        int cc = col0 + wc * 64 + ni * 16 + lcol;
        #pragma unroll
        for (int r = 0; r < 4; r++)
          Cf[(size_t)(rr + r) * 4096 + cc] = acc[mi][ni][r];
      }
    }
  } else if (EPI == 2) {
    const float* Xf = (const float*)Xv;
    const unsigned short* Xh = (const unsigned short*)Xv;
    float part = 0.f;
    #pragma unroll
    for (int mi = 0; mi < 4; mi++) {
      int rr = row0 + wr * 64 + mi * 16 + lrow;
      #pragma unroll
      for (int ni = 0; ni < 4; ni++) {
        int cc = col0 + wc * 64 + ni * 16 + lcol;
        if (cc < Nc) {
          float cd = coldiv ? coldiv[cc] : 1.f;
          #pragma unroll
          for (int r = 0; r < 4; r++) {
            float v = acc[mi][ni][r];
            if (rowdiv) v /= rowdiv[rr + r];
            v /= cd;
            size_t xi = (size_t)(rr + r) * ldX + cc;
            float xval = XBF ? bf2f(Xh[xi]) : Xf[xi];
            float d = xval - v;
            part = fmaf(d, d, part);
          }
        }
      }
    }
    part = blk_red<false>(part);
    if (t == 0) {
      float wgt = (sym && col0 > row0) ? 2.f : 1.f;
      atomicAdd(slot, part * wgt);
    }
  } else { // EPI 3
    const unsigned short* Ph = (const unsigned short*)Xv;
    float a = 0.f, sp = 0.f;
    #pragma unroll
    for (int mi = 0; mi < 4; mi++) {
      int rr = row0 + wr * 64 + mi * 16 + lrow;
      #pragma unroll
      for (int ni = 0; ni < 4; ni++) {
        int cc = col0 + wc * 64 + ni * 16 + lcol;
        #pragma unroll
        for (int r = 0; r < 4; r++) {
          float g = acc[mi][ni][r];
          float p = bf2f(Ph[(size_t)(rr + r) * ldX + cc]);
          float d2 = rowdiv[rr + r] + coldiv[cc] - 2.f * g;
          a = fmaf(p, sqrtf(fmaxf(d2, 1e-12f)), a);
          sp = fmaf(p, logf(p + 1e-10f), sp);
        }
      }
    }
    a = blk_red<false>(a);
    sp = blk_red<false>(sp);
    if (t == 0) { atomicAdd(&slot[ALN], a); atomicAdd(&slot[SPS], sp); }
  }
}

// ============ narrow split-K bf16 MFMA: C[4096][Nc<=128] += A @ Bt^T ============
__global__ __launch_bounds__(256)
void ns_mfma_k(const unsigned short* __restrict__ A, const unsigned short* __restrict__ Bt,
               float* __restrict__ C, int Nc, int K, int KC, int ldC)
{
  __shared__ unsigned short AB[2 * 8192];
  int ks = blockIdx.x & 15, strip = blockIdx.x >> 4;
  const int row0 = strip * 128;
  const int kbase = ks * KC;

  const int t = threadIdx.x, l = t & 63, wv = t >> 6;
  const int wr = wv >> 1, wc = wv & 1;
  const int lr = l & 15, lkh = (l >> 4) << 3;

  f32x4 acc[4][4];
  #pragma unroll
  for (int i = 0; i < 4; i++)
    #pragma unroll
    for (int j = 0; j < 4; j++) acc[i][j] = (f32x4){0.f, 0.f, 0.f, 0.f};

  const int srow = l >> 2;
  const int sk   = (l & 3) << 3;
  const unsigned short* Ab = A  + (size_t)(row0 + srow) * K + kbase + sk;
  const unsigned short* Bb = Bt + (size_t)srow * K + kbase + sk;

  const int NT = KC >> 5;

  auto STAGE = [&](int kt, int buf) {
    unsigned short* As = AB + buf * 8192;
    unsigned short* Bs = As + 4096;
    int k0 = kt << 5;
    #pragma unroll
    for (int h2 = 0; h2 < 2; h2++) {
      int c = wv * 2 + h2;
      gload16(Ab + (size_t)c * 16 * K + k0, As + c * 512);
      gload16(Bb + (size_t)c * 16 * K + k0, Bs + c * 512);
    }
  };

  STAGE(0, 0);
  if (NT > 1) STAGE(1, 1);
  int cur = 0;

  for (int kt = 0; kt < NT; ++kt) {
    if (kt + 1 < NT) { VMW(4); }
    else             { VMW(0); }
    __builtin_amdgcn_sched_barrier(0);
    __builtin_amdgcn_s_barrier();

    const unsigned short* As = AB + cur * 8192;
    const unsigned short* Bs = As + 4096;
    u16x8 af[4], bfv[4];
    #pragma unroll
    for (int mi = 0; mi < 4; mi++)
      af[mi] = *(const u16x8*)&As[(wr * 64 + mi * 16 + lr) * 32 + lkh];
    #pragma unroll
    for (int ni = 0; ni < 4; ni++)
      bfv[ni] = *(const u16x8*)&Bs[(wc * 64 + ni * 16 + lr) * 32 + lkh];
    #pragma unroll
    for (int mi = 0; mi < 4; mi++)
      #pragma unroll
      for (int ni = 0; ni < 4; ni++)
        acc[mi][ni] = __builtin_amdgcn_mfma_f32_16x16x32_bf16(
            __builtin_bit_cast(bf16x8, af[mi]),
            __builtin_bit_cast(bf16x8, bfv[ni]), acc[mi][ni], 0, 0, 0);

    __builtin_amdgcn_s_barrier();
    if (kt + 2 < NT) STAGE(kt + 2, cur);
    cur ^= 1;
  }

  const int lcol = l & 15, lrow = (l >> 4) << 2;
  #pragma unroll
  for (int mi = 0; mi < 4; mi++) {
    int rr = row0 + wr * 64 + mi * 16 + lrow;
    #pragma unroll
    for (int ni = 0; ni < 4; ni++) {
      int cc = wc * 64 + ni * 16 + lcol;
      if (cc < Nc) {
        #pragma unroll
        for (int r = 0; r < 4; r++)
          atomicAdd(&C[(size_t)(rr + r) * ldC + cc], acc[mi][ni][r]);
      }
    }
  }
}

// ---------------- conversion / transpose pre-passes ----------------
__global__ void cvt_k(const float* __restrict__ s, unsigned short* __restrict__ d,
                      int n8, float scale)
{
  int i = blockIdx.x * 256 + threadIdx.x;
  if (i < n8) {
    float4 a = ((const float4*)s)[2 * i], b = ((const float4*)s)[2 * i + 1];
    u16x8 w;
    w[0] = f2bf(a.x * scale); w[1] = f2bf(a.y * scale);
    w[2] = f2bf(a.z * scale); w[3] = f2bf(a.w * scale);
    w[4] = f2bf(b.x * scale); w[5] = f2bf(b.y * scale);
    w[6] = f2bf(b.z * scale); w[7] = f2bf(b.w * scale);
    ((u16x8*)d)[i] = w;
  }
}

// msk [4096][4096] fp32 -> bf16 + fused row sums (mrs pre-zeroed)
__global__ void cvt_rs_k(const float* __restrict__ s, unsigned short* __restrict__ d,
                         float* __restrict__ mrs)
{
  int i = blockIdx.x * 256 + threadIdx.x;    // chunk of 8 elems, 512 chunks/row
  float4 a = ((const float4*)s)[2 * i], b = ((const float4*)s)[2 * i + 1];
  u16x8 w;
  w[0] = f2bf(a.x); w[1] = f2bf(a.y); w[2] = f2bf(a.z); w[3] = f2bf(a.w);
  w[4] = f2bf(b.x); w[5] = f2bf(b.y); w[6] = f2bf(b.z); w[7] = f2bf(b.w);
  ((u16x8*)d)[i] = w;
  float s8 = a.x + a.y + a.z + a.w + b.x + b.y + b.z + b.w;
  float ws = wave_red_sum(s8);
  if ((threadIdx.x & 63) == 0) atomicAdd(&mrs[i >> 9], ws);
}

// [4096][3000] fp32 -> [4096][3072] bf16 zero-padded
__global__ void cvt_pad_k(const float* __restrict__ s, unsigned short* __restrict__ d)
{
  int i = blockIdx.x * 256 + threadIdx.x;
  int row = i / 384, c8 = (i - row * 384) * 8;
  u16x8 w = (u16x8)0;
  if (c8 < kIN) {
    const float* sp = s + (size_t)row * kIN + c8;
    float4 a = *(const float4*)sp, b = *(const float4*)(sp + 4);
    w[0] = f2bf(a.x); w[1] = f2bf(a.y); w[2] = f2bf(a.z); w[3] = f2bf(a.w);
    w[4] = f2bf(b.x); w[5] = f2bf(b.y); w[6] = f2bf(b.z); w[7] = f2bf(b.w);
  }
  ((u16x8*)d)[i] = w;
}

// fused: HH [4096][128] cols 0..63 -> h bf16 [4096][64] + per-row sq-norm.
// grid 1024 x 256 (1 wave per row)
__global__ void cvtsq_k(const float* __restrict__ H, unsigned short* __restrict__ hb,
                        float* __restrict__ outv)
{
  int row = blockIdx.x * 4 + (threadIdx.x >> 6), j = threadIdx.x & 63;
  float v = H[(size_t)row * 128 + j];
  hb[(size_t)row * 64 + j] = f2bf(v);
  float p = wave_red_sum(v * v);
  if (j == 0) outv[row] = p;
}

// transpose+convert: src fp32 [R][C] (ld sld) -> dst bf16 (ld dld), optional relu
template<bool RELU>
__global__ void tr_k(const float* __restrict__ src, unsigned short* __restrict__ dst,
                     int R, int C, int sld, int dld)
{
  __shared__ float tile[32][33];
  int c0 = blockIdx.x * 32, r0 = blockIdx.y * 32;
  int tr_ = threadIdx.x >> 3, tc4 = (threadIdx.x & 7) << 2;
  #pragma unroll
  for (int j = 0; j < 4; j++) {
    int r = r0 + tr_, c = c0 + tc4 + j;
    float v = (r < R && c < C) ? src[(size_t)r * sld + c] : 0.f;
    if (RELU) v = fmaxf(v, 0.f);
    tile[tr_][tc4 + j] = v;
  }
  __syncthreads();
  u16x4 wv;
  #pragma unroll
  for (int j = 0; j < 4; j++) wv[j] = f2bf(tile[tc4 + j][tr_]);
  *(u16x4*)&dst[(size_t)(c0 + tr_) * dld + r0 + tc4] = wv;
}

// bf16 -> bf16 transpose: src [R][C] -> dst [C][R]. grid (C/32, R/32)
__global__ void tr_bf_k(const unsigned short* __restrict__ src,
                        unsigned short* __restrict__ dst, int R, int C)
{
  __shared__ unsigned short tile[32][36];
  int c0 = blockIdx.x * 32, r0 = blockIdx.y * 32;
  int tr_ = threadIdx.x >> 3, tc4 = (threadIdx.x & 7) << 2;
  *(u16x4*)&tile[tr_][tc4] = *(const u16x4*)&src[(size_t)(r0 + tr_) * C + c0 + tc4];
  __syncthreads();
  u16x4 w;
  #pragma unroll
  for (int j = 0; j < 4; j++) w[j] = tile[tc4 + j][tr_];
  *(u16x4*)&dst[(size_t)(c0 + tr_) * R + r0 + tc4] = w;
}

// ---------------- small fp32 GEMM (64-col weight GEMMs), optional relu(A) -----
template<bool RELU>
__global__ __launch_bounds__(256)
void gemm_small_k(const float* __restrict__ A, const float* __restrict__ B,
                  float* __restrict__ C, int M, int Nc, int K,
                  int ldA, int ldB, int ldC)
{
  __shared__ float As[16][68];
  __shared__ float Bs[16][68];
  int tid = threadIdx.x;
  int tx = tid & 15, ty = tid >> 4;
  int row0 = blockIdx.y * 64, col0 = blockIdx.x * 64;
  float acc[4][4] = {};

  for (int k0 = 0; k0 < K; k0 += 16) {
    {
      int m = tid >> 2, kk = (tid & 3) << 2;
      const float* ap = A + (size_t)(row0 + m) * ldA + k0 + kk;
      float4 v = *(const float4*)ap;
      if (RELU) {
        v.x = fmaxf(v.x, 0.f); v.y = fmaxf(v.y, 0.f);
        v.z = fmaxf(v.z, 0.f); v.w = fmaxf(v.w, 0.f);
      }
      As[kk + 0][m] = v.x; As[kk + 1][m] = v.y; As[kk + 2][m] = v.z; As[kk + 3][m] = v.w;
    }
    {
      int kk = tid >> 4, c = (tid & 15) << 2;
      const float* bp = B + (size_t)(k0 + kk) * ldB + col0 + c;
      #pragma unroll
      for (int i = 0; i < 4; i++)
        Bs[kk][c + i] = (col0 + c + i < Nc) ? bp[i] : 0.f;
    }
    __syncthreads();
    #pragma unroll
    for (int kk = 0; kk < 16; kk++) {
      float4 a4 = *(const float4*)&As[kk][ty << 2];
      float4 b4 = *(const float4*)&Bs[kk][tx << 2];
      float av[4] = {a4.x, a4.y, a4.z, a4.w};
      float bv[4] = {b4.x, b4.y, b4.z, b4.w};
      #pragma unroll
      for (int i = 0; i < 4; i++)
        #pragma unroll
        for (int j = 0; j < 4; j++)
          acc[i][j] = fmaf(av[i], bv[j], acc[i][j]);
    }
    __syncthreads();
  }
  #pragma unroll
  for (int i = 0; i < 4; i++) {
    int r = row0 + (ty << 2) + i;
    #pragma unroll
    for (int j = 0; j < 4; j++) {
      int c = col0 + (tx << 2) + j;
      if (c < Nc) C[(size_t)r * ldC + c] = acc[i][j];
    }
  }
}

// ---------------- fused Sinkhorn passes ----------------
__global__ __launch_bounds__(256)
void sink_k(float* __restrict__ P, unsigned short* __restrict__ Pb,
            const float* __restrict__ cs_in, float* __restrict__ cs_out,
            float* __restrict__ rs, int mode)
{
  int tid = threadIdx.x;
  int r0 = blockIdx.x * 8;
  float csl[16] = {};
  float cdiv[16];
  if (mode != 0) {
    #pragma unroll
    for (int t = 0; t < 4; t++) {
      float4 c4 = ((const float4*)cs_in)[tid + t * 256];
      cdiv[4 * t + 0] = 1.f / (4096.f * c4.x);
      cdiv[4 * t + 1] = 1.f / (4096.f * c4.y);
      cdiv[4 * t + 2] = 1.f / (4096.f * c4.z);
      cdiv[4 * t + 3] = 1.f / (4096.f * c4.w);
    }
  }
  for (int rr = 0; rr < 8; rr++) {
    int row = r0 + rr;
    float4* prow = (float4*)(P + (size_t)row * 4096);
    float4 r[4];
    #pragma unroll
    for (int t = 0; t < 4; t++) r[t] = prow[tid + t * 256];

    if (mode == 0) {
      float m = -3.4e38f;
      #pragma unroll
      for (int t = 0; t < 4; t++)
        m = fmaxf(m, fmaxf(fmaxf(r[t].x, r[t].y), fmaxf(r[t].z, r[t].w)));
      m = blk_red<true>(m);
      float s = 0.f;
      #pragma unroll
      for (int t = 0; t < 4; t++) {
        r[t].x = expf(r[t].x - m); r[t].y = expf(r[t].y - m);
        r[t].z = expf(r[t].z - m); r[t].w = expf(r[t].w - m);
        s += r[t].x + r[t].y + r[t].z + r[t].w;
      }
      s = blk_red<false>(s);
      float f = 1.f / (s * 4096.f);
      #pragma unroll
      for (int t = 0; t < 4; t++) {
        r[t].x *= f; r[t].y *= f; r[t].z *= f; r[t].w *= f;
        prow[tid + t * 256] = r[t];
        csl[4 * t + 0] += r[t].x; csl[4 * t + 1] += r[t].y;
        csl[4 * t + 2] += r[t].z; csl[4 * t + 3] += r[t].w;
      }
    } else {
      float s = 0.f;
      #pragma unroll
      for (int t = 0; t < 4; t++) {
        r[t].x *= cdiv[4 * t + 0]; r[t].y *= cdiv[4 * t + 1];
        r[t].z *= cdiv[4 * t + 2]; r[t].w *= cdiv[4 * t + 3];
        s += r[t].x + r[t].y + r[t].z + r[t].w;
      }
      s = blk_red<false>(s);
      if (mode == 1) {
        float f = 1.f / (4096.f * s);
        #pragma unroll
        for (int t = 0; t < 4; t++) {
          r[t].x *= f; r[t].y *= f; r[t].z *= f; r[t].w *= f;
          prow[tid + t * 256] = r[t];
          csl[4 * t + 0] += r[t].x; csl[4 * t + 1] += r[t].y;
          csl[4 * t + 2] += r[t].z; csl[4 * t + 3] += r[t].w;
        }
      } else {
        if (tid == 0) rs[row] = s;
        #pragma unroll
        for (int t = 0; t < 4; t++) {
          prow[tid + t * 256] = r[t];
          u16x4 w;
          w[0] = f2bf(r[t].x); w[1] = f2bf(r[t].y);
          w[2] = f2bf(r[t].z); w[3] = f2bf(r[t].w);
          *(u16x4*)&Pb[(size_t)row * 4096 + 4 * (tid + t * 256)] = w;
          csl[4 * t + 0] += r[t].x; csl[4 * t + 1] += r[t].y;
          csl[4 * t + 2] += r[t].z; csl[4 * t + 3] += r[t].w;
        }
      }
    }
  }
  #pragma unroll
  for (int t = 0; t < 4; t++) {
    int j = 4 * (tid + t * 256);
    atomicAdd(&cs_out[j + 0], csl[4 * t + 0]);
    atomicAdd(&cs_out[j + 1], csl[4 * t + 1]);
    atomicAdd(&cs_out[j + 2], csl[4 * t + 2]);
    atomicAdd(&cs_out[j + 3], csl[4 * t + 3]);
  }
}

__global__ void gather_k(float* __restrict__ XP, const int* __restrict__ perm)
{
  int gid = blockIdx.x * 256 + threadIdx.x;
  int i = gid >> 6, j = gid & 63;
  XP[(size_t)i * 128 + 64 + j] = XP[(size_t)perm[i] * 128 + j];
}

__global__ void readout_k(const float* __restrict__ vs2, const float* __restrict__ mrs,
                          float* __restrict__ g2)
{
  int q = blockIdx.x, j = threadIdx.x;
  float v = vs2[(size_t)q * 64 + j] / mrs[q >> 1];
  float p = v * v;
  #pragma unroll
  for (int s = 1; s < 64; s <<= 1) p += __shfl_xor(p, s, 64);
  float nrm = sqrtf(p);
  v = v / fmaxf(nrm, 1e-12f);
  g2[(size_t)q * 64 + j] = 1.f / (1.f + expf(-v));
}

__device__ __forceinline__ float bce_term(float x, float y) {
  return fmaxf(x, 0.f) - x * y + log1pf(expf(-fabsf(x)));
}

__global__ void disc_k(const float* __restrict__ G2, const float* __restrict__ W2,
                       const float* __restrict__ lab, const float* __restrict__ bptr,
                       float* __restrict__ acc)
{
  int i = blockIdx.x, j = threadIdx.x;
  float gj  = G2[(size_t)(2 * i) * 64 + j];
  float gaj = G2[(size_t)(2 * i + 1) * 64 + j];
  float hw  = W2[(size_t)(2 * i) * 64 + j];
  float haw = W2[(size_t)(2 * i + 1) * 64 + j];
  float s1 = hw * gj, s2 = haw * gj, s1a = haw * gaj, s2a = hw * gaj;
  #pragma unroll
  for (int s = 1; s < 64; s <<= 1) {
    s1  += __shfl_xor(s1, s, 64);
    s2  += __shfl_xor(s2, s, 64);
    s1a += __shfl_xor(s1a, s, 64);
    s2a += __shfl_xor(s2a, s, 64);
  }
  if (j == 0) {
    float b = bptr[0];
    float y0 = lab[i * 2 + 0], y1 = lab[i * 2 + 1];
    float t = bce_term(s1 + b, y0) + bce_term(s2 + b, y1)
            + bce_term(s1a + b, y0) + bce_term(s2a + b, y1);
    atomicAdd(&acc[SL], t);
  }
}

__global__ __launch_bounds__(256)
void finalize_k(const float* __restrict__ acc, const float* __restrict__ cs,
                float* __restrict__ out)
{
  int tid = threadIdx.x;
  float invm2 = 1.f / (float)kN;
  float t = 0.f;
  for (int j = tid; j < kN; j += 256) {
    float q = cs[j];
    t += q * (logf(q) - invm2);
  }
  t = blk_red<false>(t);
  if (tid == 0) {
    float kld_pq = t * invm2;
    float kld_pp = invm2 * (logf(invm2) - invm2);
    out[0] = acc[SL] / (2.f * (float)kN);
    out[1] = acc[FEAT] / ((float)kN * (float)kIN);
    out[2] = acc[ALN];
    out[3] = (acc[FXA] + acc[FXB]) / ((float)kN * (float)kIN);
    out[4] = sqrtf(acc[SM1]) / (float)kN + sqrtf(acc[SM2]) / (float)kN;
    out[5] = (kld_pq - kld_pp) * (float)kN;
    out[6] = -acc[SPS];
  }
}

extern "C" void kernel_launch(void* const* d_in, const int* in_sizes, int n_in,
                              void* d_out, int out_size, void* d_ws, size_t ws_size,
                              hipStream_t stream)
{
  (void)in_sizes; (void)n_in; (void)out_size; (void)ws_size;
  const float* feat  = (const float*)d_in[0];
  const float* adjs  = (const float*)d_in[1];
  const float* gmask = (const float*)d_in[2];
  const float* labs  = (const float*)d_in[3];
  const float* dists = (const float*)d_in[4];
  const int*   perms = (const int*)d_in[5];
  const float* encW  = (const float*)d_in[6];
  const float* decW  = (const float*)d_in[7];
  const float* MsW   = (const float*)d_in[8];
  const float* discW = (const float*)d_in[9];
  const float* discb = (const float*)d_in[10];
  float* out = (float*)d_out;

  const size_t SZNN = (size_t)kN * kN;

  char* cur = (char*)d_ws;
  auto alloc = [&](size_t bytes) {
    char* p = cur;
    cur += (bytes + 255) & ~(size_t)255;
    return p;
  };
  float* P            = (float*)alloc(SZNN * 4);          // fp32 P; later reused for Tb
  unsigned short* Pb  = (unsigned short*)alloc(SZNN * 2);
  unsigned short* PbT = (unsigned short*)alloc(SZNN * 2);
  unsigned short* Db  = (unsigned short*)alloc(SZNN * 2);
  unsigned short* ajb = (unsigned short*)alloc(SZNN * 2); // adj/msk bf16; later ftb
  unsigned short* xb0 = (unsigned short*)alloc((size_t)kN * kINp * 2);
  unsigned short* xb1 = (unsigned short*)alloc((size_t)kN * kINp * 2);
  unsigned short* dWtb= (unsigned short*)alloc((size_t)kINp * kLAT * 2);
  unsigned short* ahb = (unsigned short*)alloc((size_t)kN * kLAT * 2);
  unsigned short* encWtp = (unsigned short*)alloc((size_t)128 * kINp * 2);
  unsigned short* XPt = (unsigned short*)alloc((size_t)128 * kN * 2);
  unsigned short* hbTp= (unsigned short*)alloc((size_t)128 * kN * 2);
  unsigned short* HRt = (unsigned short*)alloc((size_t)128 * kN * 2);
  unsigned short* smb = (unsigned short*)alloc((size_t)kN * kLAT * 2);
  unsigned short* tmb = (unsigned short*)alloc((size_t)kN * kLAT * 2);
  unsigned short* h0b = (unsigned short*)alloc((size_t)kN * kLAT * 2);
  unsigned short* h1b = (unsigned short*)alloc((size_t)kN * kLAT * 2);
  float* XP  = (float*)alloc((size_t)kN * 128 * 4);
  float* HH0 = (float*)alloc((size_t)kN * 128 * 4);
  float* HH1 = (float*)alloc((size_t)kN * 128 * 4);
  float* VS  = (float*)alloc((size_t)kN * 128 * 4);
  float* G2  = (float*)alloc((size_t)kN * 128 * 4);
  float* W2  = (float*)alloc((size_t)kN * 128 * 4);
  float* SM_ = (float*)alloc((size_t)kN * kLAT * 4);
  float* TM_ = (float*)alloc((size_t)kN * kLAT * 4);
  float* ah  = (float*)alloc((size_t)kN * kLAT * 4);
  float* sns = (float*)alloc(kN * 4);
  float* snt = (float*)alloc(kN * 4);
  float* rs  = (float*)alloc(kN * 4);
  float* cs  = (float*)alloc(kN * 4);
  float* csA = (float*)alloc(kN * 4);
  float* csB = (float*)alloc(kN * 4);
  float* mrs = (float*)alloc(kN * 4);
  float* acc = (float*)alloc(NSLOT * 4);

  unsigned short* Tb  = (unsigned short*)P;     // alias: fp32 P dead before Tb written
  unsigned short* ftb = ajb;                    // alias: adj/msk bf16 dead after slices

  hipMemsetAsync(acc, 0, NSLOT * sizeof(float), stream);

  // ---------------- per-slice losses ----------------
  for (int k = 0; k < 2; k++) {
    const float* x    = feat  + (size_t)k * kN * kIN;
    const float* adj  = adjs  + (size_t)k * SZNN;
    const float* msk  = gmask + (size_t)k * SZNN;
    const float* lab  = labs  + (size_t)k * kN * 2;
    const int*   perm = perms + (size_t)k * kN;
    const float* eW   = encW  + (size_t)k * kIN * kLAT;
    const float* dW   = decW  + (size_t)k * kLAT * kIN;
    float* HHk = (k == 0) ? HH0 : HH1;
    unsigned short* xbk = (k == 0) ? xb0 : xb1;

    cvt_pad_k<<<6144, 256, 0, stream>>>(x, xbk);
    hipMemsetAsync(encWtp, 0, (size_t)128 * kINp * 2, stream);
    tr_k<false><<<dim3(2, (kIN + 31) / 32), 256, 0, stream>>>(eW, encWtp, kIN, kLAT, kLAT, kINp);
    hipMemsetAsync(XP, 0, (size_t)kN * 128 * 4, stream);
    ns_mfma_k<<<512, 256, 0, stream>>>(xbk, encWtp, XP, kLAT, kINp, kINp / 16, 128);
    gather_k<<<kN * 64 / 256, 256, 0, stream>>>(XP, perm);
    tr_k<false><<<dim3(4, 128), 256, 0, stream>>>(XP, XPt, kN, 128, 128, kN);
    cvt_k<<<(int)(SZNN / 8 / 256), 256, 0, stream>>>(adj, ajb, (int)(SZNN / 8), 1.f);
    hipMemsetAsync(HHk, 0, (size_t)kN * 128 * 4, stream);
    ns_mfma_k<<<512, 256, 0, stream>>>(ajb, XPt, HHk, 128, kN, kN / 16, 128);
    hipMemsetAsync(hbTp, 0, (size_t)128 * kN * 2, stream);
    tr_k<false><<<dim3(2, 128), 256, 0, stream>>>(HHk, hbTp, kN, kLAT, 128, kN);
    hipMemsetAsync(ah, 0, (size_t)kN * kLAT * 4, stream);
    ns_mfma_k<<<512, 256, 0, stream>>>(ajb, hbTp, ah, kLAT, kN, kN / 16, kLAT);
    cvt_k<<<128, 256, 0, stream>>>(ah, ahb, kN * kLAT / 8, 1.f);
    tr_k<false><<<dim3(kINp / 32, 2), 256, 0, stream>>>(dW, dWtb, kLAT, kIN, kIN, kLAT);
    bt_mfma_k<2, 1><<<(kINp / 128) * 32, 256, 0, stream>>>(
        ahb, dWtb, nullptr, nullptr, xbk, nullptr, nullptr, &acc[FEAT],
        kINp / 128, kIN, kLAT, kINp, 0);
    // relu'd transpose for VS GEMM (reads HH directly)
    tr_k<true><<<dim3(4, 128), 256, 0, stream>>>(HHk, HRt, kN, 128, 128, kN);
    hipMemsetAsync(mrs, 0, kN * 4, stream);
    cvt_rs_k<<<(int)(SZNN / 8 / 256), 256, 0, stream>>>(msk, ajb, mrs);
    hipMemsetAsync(VS, 0, (size_t)kN * 128 * 4, stream);
    ns_mfma_k<<<512, 256, 0, stream>>>(ajb, HRt, VS, 128, kN, kN / 16, 128);
    readout_k<<<2 * kN, 64, 0, stream>>>(VS, mrs, G2);
    // W2 = relu(HH view [8192][64]) @ discW  (relu fused into A-load)
    gemm_small_k<true><<<dim3(1, 128), 256, 0, stream>>>(HHk, discW, W2, 2 * kN, kLAT,
                                                         kLAT, kLAT, kLAT, kLAT);
    disc_k<<<kN, 64, 0, stream>>>(G2, W2, lab, discb, acc);
  }

  // ---------------- alignment losses ----------------
  const float* D0 = dists;
  const float* D1 = dists + SZNN;

  gemm_small_k<false><<<dim3(1, 64), 256, 0, stream>>>(HH0, MsW, SM_, kN, kLAT, kLAT,
                                                       128, kLAT, kLAT);
  gemm_small_k<false><<<dim3(1, 64), 256, 0, stream>>>(HH1, MsW, TM_, kN, kLAT, kLAT,
                                                       128, kLAT, kLAT);
  cvt_k<<<128, 256, 0, stream>>>(SM_, smb, kN * kLAT / 8, 0.125f);
  cvt_k<<<128, 256, 0, stream>>>(TM_, tmb, kN * kLAT / 8, 1.f);
  // P = srcM @ tgtM^T / 8  (128-tile MFMA, fp32 store)
  bt_mfma_k<1, 0><<<1024, 256, 0, stream>>>(smb, tmb, nullptr, P, nullptr, nullptr, nullptr,
                                            nullptr, 32, kN, kLAT, 0, 0);

  // fused sinkhorn: softmax + 3 iters + final marginals + bf16 P, 4 passes
  hipMemsetAsync(csA, 0, kN * 4, stream);
  sink_k<<<512, 256, 0, stream>>>(P, nullptr, nullptr, csA, nullptr, 0);
  hipMemsetAsync(csB, 0, kN * 4, stream);
  sink_k<<<512, 256, 0, stream>>>(P, nullptr, csA, csB, nullptr, 1);
  hipMemsetAsync(csA, 0, kN * 4, stream);
  sink_k<<<512, 256, 0, stream>>>(P, nullptr, csB, csA, nullptr, 1);
  hipMemsetAsync(cs, 0, kN * 4, stream);
  sink_k<<<512, 256, 0, stream>>>(P, Pb, csA, cs, rs, 2);

  // PbT = bf16(P^T) — last read of fp32 P
  tr_k<false><<<dim3(kN / 32, kN / 32), 256, 0, stream>>>(P, PbT, kN, kN, kN, kN);

  // align + sparsity: h0@h1^T (128-tile MFMA, EPI3); fused h-bf16 + sqnorms
  cvtsq_k<<<1024, 256, 0, stream>>>(HH0, h0b, sns);
  cvtsq_k<<<1024, 256, 0, stream>>>(HH1, h1b, snt);
  bt_mfma_k<3, 1><<<1024, 256, 0, stream>>>(h0b, h1b, nullptr, nullptr, Pb, sns, snt, acc,
                                            32, kN, kLAT, kN, 0);

  // loss_align_fix: all-bf16 (ftb from xb transpose; X read as bf16)
  tr_bf_k<<<dim3(kINp / 32, kN / 32), 256, 0, stream>>>(xb1, ftb, kN, kINp);
  bt_mfma_k<2, 1><<<(kINp / 128) * 32, 256, 0, stream>>>(
      Pb, ftb, nullptr, nullptr, xb0, rs, nullptr, &acc[FXA], kINp / 128, kIN, kN, kINp, 0);
  tr_bf_k<<<dim3(kINp / 32, kN / 32), 256, 0, stream>>>(xb0, ftb, kN, kINp);
  bt_mfma_k<2, 1><<<(kINp / 128) * 32, 256, 0, stream>>>(
      PbT, ftb, nullptr, nullptr, xb1, cs, nullptr, &acc[FXB], kINp / 128, kIN, kN, kINp, 0);

  // loss_maintain 1: Tb = (P@D1)/rs (dense bt) ; SM1 = sum((D0 - (Tb@P^T)/rs)^2) sym
  cvt_k<<<(int)(SZNN / 8 / 256), 256, 0, stream>>>(D1, Db, (int)(SZNN / 8), 1.f);
  bt_mfma_k<0, 0><<<1024, 256, 0, stream>>>(Pb, Db, Tb, nullptr, nullptr, rs, nullptr,
                                            nullptr, 32, kN, kN, 0, 0);
  bt_mfma_k<2, 0><<<528, 256, 0, stream>>>(Tb, Pb, nullptr, nullptr, D0, nullptr, rs,
                                           &acc[SM1], 32, kN, kN, kN, 1);
  // loss_maintain 2: Tb = (P^T@D0)/cs (dense bt) ; SM2 = sum((D1 - (Tb@P)/cs)^2) sym
  cvt_k<<<(int)(SZNN / 8 / 256), 256, 0, stream>>>(D0, Db, (int)(SZNN / 8), 1.f);
  bt_mfma_k<0, 0><<<1024, 256, 0, stream>>>(PbT, Db, Tb, nullptr, nullptr, cs, nullptr,
                                            nullptr, 32, kN, kN, 0, 0);
  bt_mfma_k<2, 0><<<528, 256, 0, stream>>>(Tb, PbT, nullptr, nullptr, D1, nullptr, cs,
                                           &acc[SM2], 32, kN, kN, kN, 1);

  finalize_k<<<1, 256, 0, stream>>>(acc, cs, out);
}